// Round 5
// baseline (6470.458 us; speedup 1.0000x reference)
//
#include <hip/hip_runtime.h>
#include <cmath>

// ---------------------------------------------------------------------------
// RQ-VAE forward, round 5.
// VQ levels moved to 3-word bf16 MFMA (split accumulator, register-resident
// A, L2-resident B, LDS-free GEMM + shuffle argmin, fused residual update
// that re-emits bf16 planes for the next level). Convs unchanged from the
// passing round-4 kernel.
//
// Workspace (floats), DA = 2097152, max DA+83886080 = 344 MB (same as r3/r4):
//   [0, DA)          : wp2/wp3/wp4/cbn fp32 + bf16 weight planes
//   DA+0             : h1 / h3 / zt / d1 / D3
//   DA+16777216      : h2 / A4 / res(fp32) / D2-tail / d2 / d3
//   DA+25165824      : A3
//   DA+33554432      : resp (3 bf16 res planes) / D1
//   DA+58720256      : z
//   DA+75497472      : cbp (3-plane bf16 codebooks, 4 levels)
// ---------------------------------------------------------------------------

typedef unsigned short u16;
typedef unsigned int   u32;
typedef __attribute__((ext_vector_type(8))) short s16x8;
typedef __attribute__((ext_vector_type(4))) short s16x4;
typedef __attribute__((ext_vector_type(4))) float f32x4;
typedef __attribute__((address_space(1))) const u32 gu32;
typedef __attribute__((address_space(3))) u32 lu32;

__device__ __forceinline__ u16 f2bf(float v) {   // RNE fp32->bf16 bits
  u32 b = __builtin_bit_cast(u32, v);
  b += 0x7FFFu + ((b >> 16) & 1u);
  return (u16)(b >> 16);
}
__device__ __forceinline__ float bf2f(u16 h) {
  u32 b = ((u32)h) << 16;
  return __builtin_bit_cast(float, b);
}

// ---------------- row vector load from LDS (aligned) ----------------
template<int RW>
__device__ __forceinline__ void load_row(const float* __restrict__ p, float* r) {
  if constexpr (RW == 5) {
    float4 a = *(const float4*)p;
    r[0]=a.x; r[1]=a.y; r[2]=a.z; r[3]=a.w; r[4]=p[4];
  } else if constexpr (RW == 6) {
    float4 a = *(const float4*)p; float2 b = *(const float2*)(p+4);
    r[0]=a.x; r[1]=a.y; r[2]=a.z; r[3]=a.w; r[4]=b.x; r[5]=b.y;
  } else if constexpr (RW == 10) {
    float4 a = *(const float4*)p; float4 b = *(const float4*)(p+4);
    float2 c = *(const float2*)(p+8);
    r[0]=a.x; r[1]=a.y; r[2]=a.z; r[3]=a.w;
    r[4]=b.x; r[5]=b.y; r[6]=b.z; r[7]=b.w; r[8]=c.x; r[9]=c.y;
  }
}

// ---------------- generic tiled direct conv (fp32 light layers) ----------
template<int OCT, int SPTH, int SPTW, int KH, int KW, int S, int ACT>
__global__ __launch_bounds__(256) void conv_tiled(
    const float* __restrict__ in, const float* __restrict__ wgt,
    const float* __restrict__ bias, float* __restrict__ out,
    int N, int Cin, int Hin, int Win, int Cout, int WT,
    int padY, int padX,
    long outBase, long outNStride, long outCStride, long outYStride, long outXStride)
{
  constexpr int CK   = 8;
  constexpr int IH   = (SPTH-1)*S + KH;
  constexpr int IWr  = (SPTW-1)*S + KW;
  constexpr int IW   = (IWr + 3) & ~3;
  constexpr int TAPS = KH*KW;
  constexpr int WST  = (OCT==64) ? 68 : 5;
  constexpr int LOC  = (OCT==64) ? 16 : 4;
  constexpr int OPT  = OCT/LOC;
  constexpr int RW   = 3*S + KW;
  constexpr int EPW  = (OCT==64) ? 65 : 257;
  constexpr int SP   = SPTH*SPTW;
  constexpr int STG  = CK*IH*IW + CK*TAPS*WST;
  constexpr int SMEMN = (STG > OCT*EPW) ? STG : OCT*EPW;
  __shared__ float smem[SMEMN];
  float* s_in = smem;
  float* s_w  = smem + CK*IH*IW;

  const int tid  = threadIdx.x;
  const int tile = blockIdx.x, ocb = blockIdx.y, n = blockIdx.z;
  const int oy0 = (tile / WT) * SPTH, ox0 = (tile % WT) * SPTW;
  const int ol  = tid % LOC;
  const int g   = tid / LOC;
  const int s0  = g * 4;
  const int sy  = s0 / SPTW, sx0 = s0 % SPTW;
  const int iy0 = oy0*S - padY, ix0 = ox0*S - padX;

  float acc[OPT][4];
#pragma unroll
  for (int o = 0; o < OPT; ++o)
#pragma unroll
    for (int j = 0; j < 4; ++j) acc[o][j] = 0.f;

  for (int c0 = 0; c0 < Cin; c0 += CK) {
    __syncthreads();
    for (int i = tid; i < CK*IH*IW; i += 256) {
      int c = i / (IH*IW), r2 = i % (IH*IW);
      int iy = r2 / IW, ix = r2 % IW;
      int gy = iy0 + iy, gx = ix0 + ix;
      float v = 0.f;
      if (c0 + c < Cin && (unsigned)gy < (unsigned)Hin && (unsigned)gx < (unsigned)Win)
        v = in[(((long)n*Cin + c0 + c)*Hin + gy)*Win + gx];
      s_in[i] = v;
    }
    for (int i = tid; i < OCT*CK*TAPS; i += 256) {
      int o = i / (CK*TAPS), ct = i % (CK*TAPS);
      int oc = ocb*OCT + o, ci = c0 + ct / TAPS;
      float v = 0.f;
      if (oc < Cout && ci < Cin)
        v = wgt[((long)oc*Cin + ci)*TAPS + (ct % TAPS)];
      s_w[ct*WST + o] = v;
    }
    __syncthreads();

    for (int c = 0; c < CK; ++c) {
#pragma unroll
      for (int ky = 0; ky < KH; ++ky) {
        float r[RW];
        load_row<RW>(&s_in[c*(IH*IW) + (sy*S + ky)*IW + sx0*S], r);
#pragma unroll
        for (int kx = 0; kx < KW; ++kx) {
          if constexpr (OCT == 64) {
            float4 w4 = *(const float4*)&s_w[(c*TAPS + ky*KW + kx)*WST + ol*4];
            float wv[4] = {w4.x, w4.y, w4.z, w4.w};
#pragma unroll
            for (int o = 0; o < 4; ++o)
#pragma unroll
              for (int j = 0; j < 4; ++j)
                acc[o][j] = fmaf(wv[o], r[j*S + kx], acc[o][j]);
          } else {
            float w = s_w[(c*TAPS + ky*KW + kx)*WST + ol];
#pragma unroll
            for (int j = 0; j < 4; ++j)
              acc[0][j] = fmaf(w, r[j*S + kx], acc[0][j]);
          }
        }
      }
    }
  }

  __syncthreads();
#pragma unroll
  for (int o = 0; o < OPT; ++o) {
    int oc = ocb*OCT + ol*OPT + o;
    float b = (oc < Cout) ? bias[oc] : 0.f;
#pragma unroll
    for (int j = 0; j < 4; ++j) {
      float v = acc[o][j] + b;
      if constexpr (ACT == 1) v = fmaxf(v, 0.f);
      else if constexpr (ACT == 2) v = tanhf(v);
      smem[(ol*OPT + o)*EPW + s0 + j] = v;
    }
  }
  __syncthreads();
  for (int i = tid; i < OCT*SP; i += 256) {
    int o = i / SP, sp = i % SP;
    int oc = ocb*OCT + o;
    if (oc < Cout) {
      int syy = sp / SPTW, sxx = sp % SPTW;
      long off = outBase + (long)n*outNStride + (long)oc*outCStride
               + (long)(oy0 + syy)*outYStride + (long)(ox0 + sxx)*outXStride;
      out[off] = smem[o*EPW + sp];
    }
  }
}

// ---------------- NCHW fp32 -> NHWC bf16 planes (swizzled), NP words -------
template<int NP>
__global__ __launch_bounds__(256) void to_nhwc_bf16(const float* __restrict__ in,
    u16* __restrict__ t, long PS, int C, int HW) {
  __shared__ float sm[32][65];
  const int n = blockIdx.z, c0 = blockIdx.y << 5, w0 = blockIdx.x << 6;
  const long ibase = ((long)n * C + c0) * HW + w0;
  for (int i = threadIdx.x; i < 2048; i += 256) {
    int c = i >> 6, w = i & 63;
    sm[c][w] = in[ibase + (long)c * HW + w];
  }
  __syncthreads();
  for (int i = threadIdx.x; i < 512; i += 256) {
    int w = i >> 3, c4 = (i & 7) << 2;
    short hv[4], mv[4], lv[4];
#pragma unroll
    for (int q = 0; q < 4; ++q) {
      float v = sm[c4 + q][w];
      u16 h = f2bf(v); hv[q] = (short)h;
      float r1 = v - bf2f(h);
      u16 m = f2bf(r1); mv[q] = (short)m;
      if (NP == 3) lv[q] = (short)f2bf(r1 - bf2f(m));
    }
    int scr = c4 ^ ((w & 3) << 3);
    long o = ((long)n * HW + w0 + w) * C + c0 + scr;
    *(s16x4*)(t + o)      = *(s16x4*)hv;
    *(s16x4*)(t + PS + o) = *(s16x4*)mv;
    if (NP == 3) *(s16x4*)(t + 2*PS + o) = *(s16x4*)lv;
  }
}

// ---------------- weight split: [oc][ic][tap] fp32 -> NP x [tap][oc][ic] ---
template<int NP>
__global__ void wsplit(const float* __restrict__ w, u16* __restrict__ dst,
                       long PS, int Cout, int Cin, int TAPS) {
  int total = TAPS * Cout * Cin;
  for (int i = blockIdx.x * 256 + threadIdx.x; i < total; i += gridDim.x * 256) {
    int ic = i % Cin; int rest = i / Cin; int oc = rest % Cout; int tap = rest / Cout;
    float v = w[((long)oc * Cin + ic) * TAPS + tap];
    u16 h = f2bf(v);
    dst[i] = h;
    float r1 = v - bf2f(h);
    u16 m = f2bf(r1);
    dst[PS + i] = m;
    if (NP == 3) dst[2*PS + i] = f2bf(r1 - bf2f(m));
  }
}

// ---------------- codebook split: 4x[1024][256] fp32 -> per-level 3 planes --
__global__ void cbsplit(const float* __restrict__ cb, u16* __restrict__ dst) {
  int total = 4 * 1024 * 256;
  for (int i = blockIdx.x * 256 + threadIdx.x; i < total; i += gridDim.x * 256) {
    int l = i >> 18, kc = i & 262143;
    float v = cb[i];
    u16 h = f2bf(v);
    float r1 = v - bf2f(h);
    u16 m = f2bf(r1);
    long b = (long)l * 786432 + kc;
    dst[b] = h;
    dst[b + 262144] = m;
    dst[b + 524288] = f2bf(r1 - bf2f(m));
  }
}

// ---------------- MFMA conv: 8x8 spatial x 64 oc, NW-word bf16 -------------
template<int KH, int KW, int ACT, int NW>
__global__ __launch_bounds__(256, 3) void conv_mfma(
    const u16* __restrict__ act, long actPS,
    const u16* __restrict__ wgt, long wgtPS,
    const float* __restrict__ bias, float* __restrict__ out,
    int Cin, int H, int W, int Cout, int WT, int padY, int padX,
    long outBase, long outNS, long outCS, long outYS, long outXS)
{
  constexpr int PH = 8 + KH - 1, PW = 8 + KW - 1;
  constexpr int PPOS = PH * PW;
  constexpr int NU = (PPOS + 15) / 16;
  constexpr int PLANE = NU * 512;
  constexpr int BUFU = NW * PLANE;
  constexpr int TAPS = KH * KW;
  constexpr int PATCHB = 2 * BUFU * 2;
  constexpr int SFLOATS = ((PATCHB > 17408) ? PATCHB : 17408) / 4;
  __shared__ float smem[SFLOATS];
  u16* patch = (u16*)smem;
  float* s_ep = smem;

  const int tid = threadIdx.x;
  const int wv = tid >> 6, ln = tid & 63;
  const int r = ln & 15, kb = ln >> 4;
  const int tile = blockIdx.x, ocb = blockIdx.y, n = blockIdx.z;
  const int oy0 = (tile / WT) * 8, ox0 = (tile % WT) * 8;
  const int y0p = oy0 - padY, x0p = ox0 - padX;
  const bool border = (y0p < 0) | (x0p < 0) | (y0p + PH > H) | (x0p + PW > W);

  const int sp = ln >> 2;
  const int cs = (ln & 3) * 8;

  int aoff0[4], xb[4];
#pragma unroll
  for (int m = 0; m < 4; ++m) {
    int pos = m * 16 + r;
    int sy = pos >> 3, sx = pos & 7;
    aoff0[m] = (sy * PW + sx) * 32;
    xb[m] = x0p + sx;
  }

  f32x4 acc[4] = {};
  f32x4 acc2[4] = {};

  const long actNS = (long)H * W * Cin;
  const long tstep = (long)Cout * Cin;
  const u16* wrow = wgt + (long)(ocb * 64 + wv * 16 + r) * Cin + kb * 8;
  const u16* gact = act + (long)n * actNS;

  if (border) {
    for (int i = tid; i < 2 * BUFU / 8; i += 256)
      ((int4*)patch)[i] = make_int4(0, 0, 0, 0);
  }
  __syncthreads();

  auto stage = [&](int b, int c0) {
    u16* bb = patch + b * BUFU;
    for (int u = wv; u < NW * NU; u += 4) {
      int pl = u / NU, up = u - pl * NU;
      u16* dst = bb + pl * PLANE + up * 512;
      int p = up * 16 + sp;
      int py = p / PW, px = p - py * PW;
      int gy = y0p + py, gx = x0p + px;
      bool valid = (p < PPOS) & ((unsigned)gy < (unsigned)H) & ((unsigned)gx < (unsigned)W);
      if (valid) {
        const u16* src = gact + pl * actPS + ((long)gy * W + gx) * Cin + c0 + cs;
        __builtin_amdgcn_global_load_lds((const gu32*)src, (lu32*)dst, 16, 0, 0);
      }
    }
  };

  stage(0, 0);
  int buf = 0;
  for (int c0 = 0; c0 < Cin; c0 += 32) {
    __syncthreads();
    s16x8 Bb[2][NW];
    {
      const u16* base = wrow + c0;
#pragma unroll
      for (int p = 0; p < NW; ++p) Bb[0][p] = *(const s16x8*)(base + p * wgtPS);
    }
    if (c0 + 32 < Cin) stage(buf ^ 1, c0 + 32);
    const u16* pb = patch + buf * BUFU;
#pragma unroll
    for (int t = 0; t < TAPS; ++t) {
      if (t + 1 < TAPS) {
        const u16* base = wrow + (long)(t + 1) * tstep + c0;
#pragma unroll
        for (int p = 0; p < NW; ++p)
          Bb[(t + 1) & 1][p] = *(const s16x8*)(base + p * wgtPS);
      }
      const int ky = t / KW, kx = t % KW;
#pragma unroll
      for (int m = 0; m < 4; ++m) {
        const int key = (xb[m] + kx) & 3;
        const int aoff = aoff0[m] + (ky * PW + kx) * 32 + ((kb ^ key) * 8);
        s16x8 a[NW];
#pragma unroll
        for (int p = 0; p < NW; ++p)
          a[p] = *(const s16x8*)(pb + p * PLANE + aoff);
        acc[m] = __builtin_amdgcn_mfma_f32_16x16x32_bf16(a[0], Bb[t & 1][0], acc[m], 0, 0, 0);
        if constexpr (NW == 2) {
          acc[m] = __builtin_amdgcn_mfma_f32_16x16x32_bf16(a[1], Bb[t & 1][0], acc[m], 0, 0, 0);
          acc[m] = __builtin_amdgcn_mfma_f32_16x16x32_bf16(a[0], Bb[t & 1][1], acc[m], 0, 0, 0);
        } else {
          acc2[m] = __builtin_amdgcn_mfma_f32_16x16x32_bf16(a[1], Bb[t & 1][0], acc2[m], 0, 0, 0);
          acc2[m] = __builtin_amdgcn_mfma_f32_16x16x32_bf16(a[0], Bb[t & 1][1], acc2[m], 0, 0, 0);
          acc2[m] = __builtin_amdgcn_mfma_f32_16x16x32_bf16(a[2], Bb[t & 1][0], acc2[m], 0, 0, 0);
          acc2[m] = __builtin_amdgcn_mfma_f32_16x16x32_bf16(a[0], Bb[t & 1][2], acc2[m], 0, 0, 0);
          acc2[m] = __builtin_amdgcn_mfma_f32_16x16x32_bf16(a[1], Bb[t & 1][1], acc2[m], 0, 0, 0);
        }
      }
    }
    buf ^= 1;
  }

  __syncthreads();
  const float bsv = bias[ocb * 64 + wv * 16 + r];
#pragma unroll
  for (int m = 0; m < 4; ++m) {
    f32x4 v = acc[m];
#pragma unroll
    for (int j = 0; j < 4; ++j) {
      float x = v[j];
      if constexpr (NW == 3) x += acc2[m][j];
      x += bsv;
      if (ACT == 1) x = fmaxf(x, 0.f);
      v[j] = x;
    }
    *(f32x4*)&s_ep[(wv * 16 + r) * 68 + m * 16 + kb * 4] = v;
  }
  __syncthreads();
  for (int i = tid; i < 4096; i += 256) {
    int oc = i >> 6, p2 = i & 63;
    int syy = p2 >> 3, sxx = p2 & 7;
    long off = outBase + (long)n * outNS + (long)(ocb * 64 + oc) * outCS
             + (long)(oy0 + syy) * outYS + (long)(ox0 + sxx) * outXS;
    out[off] = s_ep[oc * 68 + p2];
  }
}

// ---------------- convT weight rearrange into 4 parity 2x2 convs ------------
__global__ void rearrange_convT(const float* __restrict__ w, float* __restrict__ wp,
                                int Cin, int Cout) {
  int total = 4*Cout*Cin*4;
  for (int idx = blockIdx.x*256 + threadIdx.x; idx < total; idx += gridDim.x*256) {
    int e = idx & 1, d = (idx >> 1) & 1;
    int r = idx >> 2;
    int ic = r % Cin; r /= Cin;
    int oc = r % Cout; int p = r / Cout;
    int py = p >> 1, px = p & 1;
    int ky = py ? (d ? 0 : 2) : (d ? 1 : 3);
    int kx = px ? (e ? 0 : 2) : (e ? 1 : 3);
    wp[idx] = w[((ic*Cout + oc)*4 + ky)*4 + kx];
  }
}

// ---------------- codebook squared norms ----------------
__global__ __launch_bounds__(256) void cb_norm(const float* __restrict__ cb,
                                               float* __restrict__ outn) {
  int row = blockIdx.x;
  float v = cb[(long)row*256 + threadIdx.x];
  v *= v;
  for (int off = 32; off; off >>= 1) v += __shfl_down(v, off, 64);
  __shared__ float sr[4];
  if ((threadIdx.x & 63) == 0) sr[threadIdx.x >> 6] = v;
  __syncthreads();
  if (threadIdx.x == 0) outn[row] = sr[0] + sr[1] + sr[2] + sr[3];
}

__global__ void zero4(float* __restrict__ p) {
  if (threadIdx.x < 4) p[threadIdx.x] = 0.f;
}

// -------- z (NCHW) -> token-major zt + fp32 residual + 3 bf16 planes -------
__global__ __launch_bounds__(256) void transpose_zt(const float* __restrict__ z,
                                                    float* __restrict__ zt,
                                                    float* __restrict__ res,
                                                    u16* __restrict__ resp) {
  __shared__ float t[32][33];
  int b = blockIdx.z, c0 = blockIdx.y*32, hw0 = blockIdx.x*32;
  for (int i = threadIdx.x; i < 1024; i += 256) {
    int cc = i >> 5, ww = i & 31;
    t[cc][ww] = z[((long)(b*256 + c0 + cc) << 12) + hw0 + ww];
  }
  __syncthreads();
  for (int i = threadIdx.x; i < 1024; i += 256) {
    int ww = i >> 5, cc = i & 31;
    float v = t[cc][ww];
    long o = ((long)(b*4096 + hw0 + ww) << 8) + c0 + cc;
    zt[o] = v; res[o] = v;
    u16 h = f2bf(v);
    float r1 = v - bf2f(h);
    u16 m = f2bf(r1);
    resp[o] = h;
    resp[16777216L + o] = m;
    resp[33554432L + o] = f2bf(r1 - bf2f(m));
  }
}

// ---------------- quantized = zt - residual, token-major -> NCHW ------------
__global__ __launch_bounds__(256) void make_quantized(const float* __restrict__ zt,
                                                      const float* __restrict__ res,
                                                      float* __restrict__ q) {
  __shared__ float t[32][33];
  int b = blockIdx.z, c0 = blockIdx.y*32, hw0 = blockIdx.x*32;
  for (int i = threadIdx.x; i < 1024; i += 256) {
    int tt = i >> 5, cc = i & 31;
    long o = ((long)(b*4096 + hw0 + tt) << 8) + c0 + cc;
    t[cc][tt] = zt[o] - res[o];
  }
  __syncthreads();
  for (int i = threadIdx.x; i < 1024; i += 256) {
    int cc = i >> 5, ww = i & 31;
    q[((long)(b*256 + c0 + cc) << 12) + hw0 + ww] = t[cc][ww];
  }
}

// ---------------- one residual-VQ level, MFMA (3-word split) ---------------
// Block = 64 tokens (4 waves x 16). Wave keeps its tokens' full K=256 A
// fragments (3 planes) in registers; loops 16 chunks of 64 codes with
// double-buffered B from L2. d = cbn - 2*(acc+acc2); shuffle argmin with
// first-index ties; fused fp32 residual update + (WP) next-level planes.
template<bool WP>
__global__ __launch_bounds__(256, 2) void vq_mfma(
    const u16* __restrict__ cbp, const float* __restrict__ cb,
    const float* __restrict__ cbn,
    float* __restrict__ res, u16* __restrict__ resp,
    float* __restrict__ idx_out, float* __restrict__ loss_out)
{
  __shared__ int   s_idx[64];
  __shared__ float s_ls[4];
  const int tid = threadIdx.x;
  const int wv = tid >> 6, ln = tid & 63;
  const int r = ln & 15, kb = ln >> 4;
  const long t0 = (long)blockIdx.x * 64;
  const long tok = t0 + wv * 16 + r;

  // A fragments: 3 planes x 8 k-steps, register-resident (96 VGPR)
  s16x8 A[3][8];
#pragma unroll
  for (int p = 0; p < 3; ++p)
#pragma unroll
    for (int ks = 0; ks < 8; ++ks)
      A[p][ks] = *(const s16x8*)(resp + (long)p * 16777216 + tok * 256 + ks * 32 + kb * 8);

  float bv[4]; int bi[4];
#pragma unroll
  for (int j = 0; j < 4; ++j) { bv[j] = 3.4e38f; bi[j] = 0; }

  for (int n0 = 0; n0 < 1024; n0 += 64) {
    f32x4 acc[4] = {};
    f32x4 acc2[4] = {};
    s16x8 B[2][3][4];
#pragma unroll
    for (int p = 0; p < 3; ++p)
#pragma unroll
      for (int nt = 0; nt < 4; ++nt)
        B[0][p][nt] = *(const s16x8*)(cbp + (long)p * 262144
                                      + (long)(n0 + nt * 16 + r) * 256 + kb * 8);
#pragma unroll
    for (int ks = 0; ks < 8; ++ks) {
      if (ks + 1 < 8) {
#pragma unroll
        for (int p = 0; p < 3; ++p)
#pragma unroll
          for (int nt = 0; nt < 4; ++nt)
            B[(ks + 1) & 1][p][nt] = *(const s16x8*)(cbp + (long)p * 262144
                + (long)(n0 + nt * 16 + r) * 256 + (ks + 1) * 32 + kb * 8);
      }
      const int c = ks & 1;
#pragma unroll
      for (int nt = 0; nt < 4; ++nt) {
        acc[nt]  = __builtin_amdgcn_mfma_f32_16x16x32_bf16(A[0][ks], B[c][0][nt], acc[nt], 0, 0, 0);
        acc2[nt] = __builtin_amdgcn_mfma_f32_16x16x32_bf16(A[1][ks], B[c][0][nt], acc2[nt], 0, 0, 0);
        acc2[nt] = __builtin_amdgcn_mfma_f32_16x16x32_bf16(A[0][ks], B[c][1][nt], acc2[nt], 0, 0, 0);
        acc2[nt] = __builtin_amdgcn_mfma_f32_16x16x32_bf16(A[2][ks], B[c][0][nt], acc2[nt], 0, 0, 0);
        acc2[nt] = __builtin_amdgcn_mfma_f32_16x16x32_bf16(A[0][ks], B[c][2][nt], acc2[nt], 0, 0, 0);
        acc2[nt] = __builtin_amdgcn_mfma_f32_16x16x32_bf16(A[1][ks], B[c][1][nt], acc2[nt], 0, 0, 0);
      }
    }
    // D: col(lane&15)=code-in-tile, row(kb*4+j)=token-in-M-tile
#pragma unroll
    for (int nt = 0; nt < 4; ++nt) {
      int code = n0 + nt * 16 + r;
      float cn = cbn[code];
#pragma unroll
      for (int j = 0; j < 4; ++j) {
        float d = cn - 2.f * (acc[nt][j] + acc2[nt][j]);
        if (d < bv[j]) { bv[j] = d; bi[j] = code; }   // ascending codes: strict <
      }
    }
  }

  // cross-lane argmin over the 16 code-columns (first-index ties)
#pragma unroll
  for (int m = 1; m < 16; m <<= 1) {
#pragma unroll
    for (int j = 0; j < 4; ++j) {
      float ov = __shfl_xor(bv[j], m, 64);
      int   oi = __shfl_xor(bi[j], m, 64);
      if (ov < bv[j] || (ov == bv[j] && oi < bi[j])) { bv[j] = ov; bi[j] = oi; }
    }
  }
  if (r == 0) {
#pragma unroll
    for (int j = 0; j < 4; ++j) s_idx[wv * 16 + kb * 4 + j] = bi[j];
  }
  __syncthreads();

  // fused update: thread tid = channel c; loop tokens
  const int c = tid;
  float lsum = 0.f;
  for (int m2 = 0; m2 < 64; ++m2) {
    int w = s_idx[m2];
    long ro = (t0 + m2) * 256 + c;
    float nv = res[ro] - cb[(long)w * 256 + c];
    res[ro] = nv;
    lsum += nv * nv;
    if (WP) {
      u16 h = f2bf(nv);
      float r1 = nv - bf2f(h);
      u16 mm = f2bf(r1);
      resp[ro] = h;
      resp[16777216L + ro] = mm;
      resp[33554432L + ro] = f2bf(r1 - bf2f(mm));
    }
  }
  for (int off = 32; off; off >>= 1) lsum += __shfl_down(lsum, off, 64);
  if (ln == 0) s_ls[wv] = lsum;
  __syncthreads();
  if (tid == 0)
    atomicAdd(loss_out, (s_ls[0] + s_ls[1] + s_ls[2] + s_ls[3]) * (1.f/(65536.f*256.f)));
  if (tid < 64) {
    long tglob = t0 + tid;
    int b = (int)(tglob >> 12), hw = (int)(tglob & 4095);
    idx_out[(long)b * 16384 + hw] = (float)s_idx[tid];
  }
}

// ---------------------------------------------------------------------------
extern "C" void kernel_launch(void* const* d_in, const int* in_sizes, int n_in,
                              void* d_out, int out_size, void* d_ws, size_t ws_size,
                              hipStream_t stream) {
  const float* x      = (const float*)d_in[0];
  const float* ew1    = (const float*)d_in[1];
  const float* eb1    = (const float*)d_in[2];
  const float* ew2    = (const float*)d_in[3];
  const float* eb2    = (const float*)d_in[4];
  const float* ew3    = (const float*)d_in[5];
  const float* eb3    = (const float*)d_in[6];
  const float* ew4    = (const float*)d_in[7];
  const float* eb4    = (const float*)d_in[8];
  const float* cbooks = (const float*)d_in[9];
  const float* dw1    = (const float*)d_in[10];
  const float* db1    = (const float*)d_in[11];
  const float* dw2    = (const float*)d_in[12];
  const float* db2    = (const float*)d_in[13];
  const float* dw3    = (const float*)d_in[14];
  const float* db3    = (const float*)d_in[15];
  const float* dw4    = (const float*)d_in[16];
  const float* db4    = (const float*)d_in[17];

  float* out = (float*)d_out;
  float* o_recon = out;                  // (16,3,512,512)
  float* o_idx   = out + 12582912;       // (16,4,64,64)
  float* o_loss  = out + 12845056;       // (4,)
  float* o_q     = out + 12845060;       // (16,256,64,64)

  float* ws  = (float*)d_ws;
  // fp32 prep region
  float* wp2 = ws;                        // 131072
  float* wp3 = ws + 131072;               //  65536
  float* wp4 = ws + 196608;               //   3072
  float* cbn = ws + 199680;               //   4096
  // bf16 weight planes (u16), base at float offset 203776
  u16* wu   = (u16*)(ws + 203776);
  u16* e3w  = wu;                         // 3 x 294912
  u16* e4w  = wu + 884736;                // 3 x 589824
  u16* d1w  = wu + 2654208;               // 2 x 294912
  u16* t2w  = wu + 3244032;               // 4 x (2 x 32768)
  u16* t3w  = wu + 3506176;               // 4 x (2 x 16384) -> ends 3637248

  const long DA = 2097152;
  float* h1  = ws + DA;
  float* h2  = ws + DA + 16777216;
  float* h3  = ws + DA;                   // h1 dead
  float* z   = ws + DA + 58720256;        // 16,777,216
  float* zt  = ws + DA;                   // h3 dead
  float* res = ws + DA + 16777216;        // A4 dead
  u16* resp  = (u16*)(ws + DA + 33554432);// 3 x 16,777,216 u16
  u16* cbp   = (u16*)(ws + DA + 75497472);// 4 x 786,432 u16 (dead before d3)
  float* d1  = ws + DA;                   // zt dead
  float* d2  = ws + DA + 16777216;        // res dead
  float* d3  = ws + DA + 16777216;        // D3 consumed
  u16* A3 = (u16*)(ws + DA + 25165824);   // 3 x 8,388,608 u16
  u16* A4 = (u16*)(ws + DA + 16777216);   // 3 x 16,777,216 u16
  u16* D1 = (u16*)(ws + DA + 33554432);   // 2 x 16,777,216 u16 (resp dead)
  u16* D2 = (u16*)(ws + DA + 8388608);    // 2 x 8,388,608 u16
  u16* D3 = (u16*)(ws + DA);              // 2 x 16,777,216 u16

  // ---------------- prep ----------------
  rearrange_convT<<<256, 256, 0, stream>>>(dw2, wp2, 128, 64);
  rearrange_convT<<<256, 256, 0, stream>>>(dw3, wp3, 64, 64);
  rearrange_convT<<<16, 256, 0, stream>>>(dw4, wp4, 64, 3);
  cb_norm<<<4096, 256, 0, stream>>>(cbooks, cbn);
  cbsplit<<<512, 256, 0, stream>>>(cbooks, cbp);
  zero4<<<1, 64, 0, stream>>>(o_loss);
  wsplit<3><<<256, 256, 0, stream>>>(ew3, e3w, 294912L, 256, 128, 9);
  wsplit<3><<<256, 256, 0, stream>>>(ew4, e4w, 589824L, 256, 256, 9);
  wsplit<2><<<256, 256, 0, stream>>>(dw1, d1w, 294912L, 128, 256, 9);
  for (int p = 0; p < 4; ++p) {
    wsplit<2><<<64, 256, 0, stream>>>(wp2 + p*32768, t2w + p*65536, 32768L, 64, 128, 4);
    wsplit<2><<<64, 256, 0, stream>>>(wp3 + p*16384, t3w + p*32768, 16384L, 64, 64, 4);
  }

  // ---------------- encoder ----------------
  conv_tiled<64,8,8,4,4,2,1><<<dim3(256,1,16), 256, 0, stream>>>(
      x, ew1, eb1, h1, 16, 3, 256, 256, 64, 16, 1, 1,
      0L, 1048576L, 16384L, 128L, 1L);
  conv_tiled<64,8,8,4,4,2,1><<<dim3(64,2,16), 256, 0, stream>>>(
      h1, ew2, eb2, h2, 16, 64, 128, 128, 128, 8, 1, 1,
      0L, 524288L, 4096L, 64L, 1L);

  to_nhwc_bf16<3><<<dim3(64,4,16), 256, 0, stream>>>(h2, A3, 8388608L, 128, 4096);
  conv_mfma<3,3,1,3><<<dim3(64,4,16), 256, 0, stream>>>(
      A3, 8388608L, e3w, 294912L, eb3, h3,
      128, 64, 64, 256, 8, 1, 1, 0L, 1048576L, 4096L, 64L, 1L);

  to_nhwc_bf16<3><<<dim3(64,8,16), 256, 0, stream>>>(h3, A4, 16777216L, 256, 4096);
  conv_mfma<3,3,0,3><<<dim3(64,4,16), 256, 0, stream>>>(
      A4, 16777216L, e4w, 589824L, eb4, z,
      256, 64, 64, 256, 8, 1, 1, 0L, 1048576L, 4096L, 64L, 1L);

  // ---------------- VQ ----------------
  transpose_zt<<<dim3(128,8,16), 256, 0, stream>>>(z, zt, res, resp);
  for (int l = 0; l < 3; ++l)
    vq_mfma<true><<<1024, 256, 0, stream>>>(cbp + (long)l*786432,
        cbooks + (long)l*262144, cbn + l*1024, res, resp,
        o_idx + l*4096, o_loss + l);
  vq_mfma<false><<<1024, 256, 0, stream>>>(cbp + 3L*786432,
      cbooks + 3L*262144, cbn + 3*1024, res, resp,
      o_idx + 3*4096, o_loss + 3);
  make_quantized<<<dim3(128,8,16), 256, 0, stream>>>(zt, res, o_q);

  // ---------------- decoder ----------------
  to_nhwc_bf16<2><<<dim3(64,8,16), 256, 0, stream>>>(o_q, D1, 16777216L, 256, 4096);
  conv_mfma<3,3,1,2><<<dim3(64,2,16), 256, 0, stream>>>(
      D1, 16777216L, d1w, 294912L, db1, d1,
      256, 64, 64, 128, 8, 1, 1, 0L, 524288L, 4096L, 64L, 1L);

  to_nhwc_bf16<2><<<dim3(64,4,16), 256, 0, stream>>>(d1, D2, 8388608L, 128, 4096);
  for (int p = 0; p < 4; ++p) {
    int py = p >> 1, px = p & 1;
    conv_mfma<2,2,1,2><<<dim3(64,1,16), 256, 0, stream>>>(
        D2, 8388608L, t2w + p*65536, 32768L, db2, d2,
        128, 64, 64, 64, 8, 1-py, 1-px,
        (long)(py*128 + px), 1048576L, 16384L, 256L, 2L);
  }

  to_nhwc_bf16<2><<<dim3(256,2,16), 256, 0, stream>>>(d2, D3, 16777216L, 64, 16384);
  for (int p = 0; p < 4; ++p) {
    int py = p >> 1, px = p & 1;
    conv_mfma<2,2,1,2><<<dim3(256,1,16), 256, 0, stream>>>(
        D3, 16777216L, t3w + p*32768, 16384L, db3, d3,
        64, 128, 128, 64, 16, 1-py, 1-px,
        (long)(py*256 + px), 4194304L, 65536L, 512L, 2L);
  }

  for (int p = 0; p < 4; ++p) {
    int py = p >> 1, px = p & 1;
    conv_tiled<4,16,16,2,2,1,2><<<dim3(256,1,16), 256, 0, stream>>>(
        d3, wp4 + p*768, db4, o_recon, 16, 64, 256, 256, 3, 16, 1-py, 1-px,
        (long)(py*512 + px), 786432L, 262144L, 1024L, 2L);
  }
  (void)in_sizes; (void)n_in; (void)out_size; (void)ws_size;
}

// Round 6
// 4141.873 us; speedup vs baseline: 1.5622x; 1.5622x over previous
//
#include <hip/hip_runtime.h>
#include <cmath>

// ---------------------------------------------------------------------------
// RQ-VAE forward, round 6.
// vq_mfma fixed: round-5's launch_bounds(256,2) + ~300-VGPR working set forced
// scratch spills (VGPR_Count=96 proved it). Now B goes through LDS (shared by
// all 4 waves, double-buffered, global_load_lds with pre-swizzled source);
// A stays register-resident (96 VGPR); total ~210 VGPR < 256 cap -> no spill.
// MFMA product order identical -> bit-identical indices. Convs unchanged.
// ---------------------------------------------------------------------------

typedef unsigned short u16;
typedef unsigned int   u32;
typedef __attribute__((ext_vector_type(8))) short s16x8;
typedef __attribute__((ext_vector_type(4))) short s16x4;
typedef __attribute__((ext_vector_type(4))) float f32x4;
typedef __attribute__((address_space(1))) const u32 gu32;
typedef __attribute__((address_space(3))) u32 lu32;

__device__ __forceinline__ u16 f2bf(float v) {   // RNE fp32->bf16 bits
  u32 b = __builtin_bit_cast(u32, v);
  b += 0x7FFFu + ((b >> 16) & 1u);
  return (u16)(b >> 16);
}
__device__ __forceinline__ float bf2f(u16 h) {
  u32 b = ((u32)h) << 16;
  return __builtin_bit_cast(float, b);
}

// ---------------- row vector load from LDS (aligned) ----------------
template<int RW>
__device__ __forceinline__ void load_row(const float* __restrict__ p, float* r) {
  if constexpr (RW == 5) {
    float4 a = *(const float4*)p;
    r[0]=a.x; r[1]=a.y; r[2]=a.z; r[3]=a.w; r[4]=p[4];
  } else if constexpr (RW == 6) {
    float4 a = *(const float4*)p; float2 b = *(const float2*)(p+4);
    r[0]=a.x; r[1]=a.y; r[2]=a.z; r[3]=a.w; r[4]=b.x; r[5]=b.y;
  } else if constexpr (RW == 10) {
    float4 a = *(const float4*)p; float4 b = *(const float4*)(p+4);
    float2 c = *(const float2*)(p+8);
    r[0]=a.x; r[1]=a.y; r[2]=a.z; r[3]=a.w;
    r[4]=b.x; r[5]=b.y; r[6]=b.z; r[7]=b.w; r[8]=c.x; r[9]=c.y;
  }
}

// ---------------- generic tiled direct conv (fp32 light layers) ----------
template<int OCT, int SPTH, int SPTW, int KH, int KW, int S, int ACT>
__global__ __launch_bounds__(256) void conv_tiled(
    const float* __restrict__ in, const float* __restrict__ wgt,
    const float* __restrict__ bias, float* __restrict__ out,
    int N, int Cin, int Hin, int Win, int Cout, int WT,
    int padY, int padX,
    long outBase, long outNStride, long outCStride, long outYStride, long outXStride)
{
  constexpr int CK   = 8;
  constexpr int IH   = (SPTH-1)*S + KH;
  constexpr int IWr  = (SPTW-1)*S + KW;
  constexpr int IW   = (IWr + 3) & ~3;
  constexpr int TAPS = KH*KW;
  constexpr int WST  = (OCT==64) ? 68 : 5;
  constexpr int LOC  = (OCT==64) ? 16 : 4;
  constexpr int OPT  = OCT/LOC;
  constexpr int RW   = 3*S + KW;
  constexpr int EPW  = (OCT==64) ? 65 : 257;
  constexpr int SP   = SPTH*SPTW;
  constexpr int STG  = CK*IH*IW + CK*TAPS*WST;
  constexpr int SMEMN = (STG > OCT*EPW) ? STG : OCT*EPW;
  __shared__ float smem[SMEMN];
  float* s_in = smem;
  float* s_w  = smem + CK*IH*IW;

  const int tid  = threadIdx.x;
  const int tile = blockIdx.x, ocb = blockIdx.y, n = blockIdx.z;
  const int oy0 = (tile / WT) * SPTH, ox0 = (tile % WT) * SPTW;
  const int ol  = tid % LOC;
  const int g   = tid / LOC;
  const int s0  = g * 4;
  const int sy  = s0 / SPTW, sx0 = s0 % SPTW;
  const int iy0 = oy0*S - padY, ix0 = ox0*S - padX;

  float acc[OPT][4];
#pragma unroll
  for (int o = 0; o < OPT; ++o)
#pragma unroll
    for (int j = 0; j < 4; ++j) acc[o][j] = 0.f;

  for (int c0 = 0; c0 < Cin; c0 += CK) {
    __syncthreads();
    for (int i = tid; i < CK*IH*IW; i += 256) {
      int c = i / (IH*IW), r2 = i % (IH*IW);
      int iy = r2 / IW, ix = r2 % IW;
      int gy = iy0 + iy, gx = ix0 + ix;
      float v = 0.f;
      if (c0 + c < Cin && (unsigned)gy < (unsigned)Hin && (unsigned)gx < (unsigned)Win)
        v = in[(((long)n*Cin + c0 + c)*Hin + gy)*Win + gx];
      s_in[i] = v;
    }
    for (int i = tid; i < OCT*CK*TAPS; i += 256) {
      int o = i / (CK*TAPS), ct = i % (CK*TAPS);
      int oc = ocb*OCT + o, ci = c0 + ct / TAPS;
      float v = 0.f;
      if (oc < Cout && ci < Cin)
        v = wgt[((long)oc*Cin + ci)*TAPS + (ct % TAPS)];
      s_w[ct*WST + o] = v;
    }
    __syncthreads();

    for (int c = 0; c < CK; ++c) {
#pragma unroll
      for (int ky = 0; ky < KH; ++ky) {
        float r[RW];
        load_row<RW>(&s_in[c*(IH*IW) + (sy*S + ky)*IW + sx0*S], r);
#pragma unroll
        for (int kx = 0; kx < KW; ++kx) {
          if constexpr (OCT == 64) {
            float4 w4 = *(const float4*)&s_w[(c*TAPS + ky*KW + kx)*WST + ol*4];
            float wv[4] = {w4.x, w4.y, w4.z, w4.w};
#pragma unroll
            for (int o = 0; o < 4; ++o)
#pragma unroll
              for (int j = 0; j < 4; ++j)
                acc[o][j] = fmaf(wv[o], r[j*S + kx], acc[o][j]);
          } else {
            float w = s_w[(c*TAPS + ky*KW + kx)*WST + ol];
#pragma unroll
            for (int j = 0; j < 4; ++j)
              acc[0][j] = fmaf(w, r[j*S + kx], acc[0][j]);
          }
        }
      }
    }
  }

  __syncthreads();
#pragma unroll
  for (int o = 0; o < OPT; ++o) {
    int oc = ocb*OCT + ol*OPT + o;
    float b = (oc < Cout) ? bias[oc] : 0.f;
#pragma unroll
    for (int j = 0; j < 4; ++j) {
      float v = acc[o][j] + b;
      if constexpr (ACT == 1) v = fmaxf(v, 0.f);
      else if constexpr (ACT == 2) v = tanhf(v);
      smem[(ol*OPT + o)*EPW + s0 + j] = v;
    }
  }
  __syncthreads();
  for (int i = tid; i < OCT*SP; i += 256) {
    int o = i / SP, sp = i % SP;
    int oc = ocb*OCT + o;
    if (oc < Cout) {
      int syy = sp / SPTW, sxx = sp % SPTW;
      long off = outBase + (long)n*outNStride + (long)oc*outCStride
               + (long)(oy0 + syy)*outYStride + (long)(ox0 + sxx)*outXStride;
      out[off] = smem[o*EPW + sp];
    }
  }
}

// ---------------- NCHW fp32 -> NHWC bf16 planes (swizzled), NP words -------
template<int NP>
__global__ __launch_bounds__(256) void to_nhwc_bf16(const float* __restrict__ in,
    u16* __restrict__ t, long PS, int C, int HW) {
  __shared__ float sm[32][65];
  const int n = blockIdx.z, c0 = blockIdx.y << 5, w0 = blockIdx.x << 6;
  const long ibase = ((long)n * C + c0) * HW + w0;
  for (int i = threadIdx.x; i < 2048; i += 256) {
    int c = i >> 6, w = i & 63;
    sm[c][w] = in[ibase + (long)c * HW + w];
  }
  __syncthreads();
  for (int i = threadIdx.x; i < 512; i += 256) {
    int w = i >> 3, c4 = (i & 7) << 2;
    short hv[4], mv[4], lv[4];
#pragma unroll
    for (int q = 0; q < 4; ++q) {
      float v = sm[c4 + q][w];
      u16 h = f2bf(v); hv[q] = (short)h;
      float r1 = v - bf2f(h);
      u16 m = f2bf(r1); mv[q] = (short)m;
      if (NP == 3) lv[q] = (short)f2bf(r1 - bf2f(m));
    }
    int scr = c4 ^ ((w & 3) << 3);
    long o = ((long)n * HW + w0 + w) * C + c0 + scr;
    *(s16x4*)(t + o)      = *(s16x4*)hv;
    *(s16x4*)(t + PS + o) = *(s16x4*)mv;
    if (NP == 3) *(s16x4*)(t + 2*PS + o) = *(s16x4*)lv;
  }
}

// ---------------- weight split: [oc][ic][tap] fp32 -> NP x [tap][oc][ic] ---
template<int NP>
__global__ void wsplit(const float* __restrict__ w, u16* __restrict__ dst,
                       long PS, int Cout, int Cin, int TAPS) {
  int total = TAPS * Cout * Cin;
  for (int i = blockIdx.x * 256 + threadIdx.x; i < total; i += gridDim.x * 256) {
    int ic = i % Cin; int rest = i / Cin; int oc = rest % Cout; int tap = rest / Cout;
    float v = w[((long)oc * Cin + ic) * TAPS + tap];
    u16 h = f2bf(v);
    dst[i] = h;
    float r1 = v - bf2f(h);
    u16 m = f2bf(r1);
    dst[PS + i] = m;
    if (NP == 3) dst[2*PS + i] = f2bf(r1 - bf2f(m));
  }
}

// ---------------- codebook split: 4x[1024][256] fp32 -> per-level 3 planes --
__global__ void cbsplit(const float* __restrict__ cb, u16* __restrict__ dst) {
  int total = 4 * 1024 * 256;
  for (int i = blockIdx.x * 256 + threadIdx.x; i < total; i += gridDim.x * 256) {
    int l = i >> 18, kc = i & 262143;
    float v = cb[i];
    u16 h = f2bf(v);
    float r1 = v - bf2f(h);
    u16 m = f2bf(r1);
    long b = (long)l * 786432 + kc;
    dst[b] = h;
    dst[b + 262144] = m;
    dst[b + 524288] = f2bf(r1 - bf2f(m));
  }
}

// ---------------- MFMA conv: 8x8 spatial x 64 oc, NW-word bf16 -------------
template<int KH, int KW, int ACT, int NW>
__global__ __launch_bounds__(256, 3) void conv_mfma(
    const u16* __restrict__ act, long actPS,
    const u16* __restrict__ wgt, long wgtPS,
    const float* __restrict__ bias, float* __restrict__ out,
    int Cin, int H, int W, int Cout, int WT, int padY, int padX,
    long outBase, long outNS, long outCS, long outYS, long outXS)
{
  constexpr int PH = 8 + KH - 1, PW = 8 + KW - 1;
  constexpr int PPOS = PH * PW;
  constexpr int NU = (PPOS + 15) / 16;
  constexpr int PLANE = NU * 512;
  constexpr int BUFU = NW * PLANE;
  constexpr int TAPS = KH * KW;
  constexpr int PATCHB = 2 * BUFU * 2;
  constexpr int SFLOATS = ((PATCHB > 17408) ? PATCHB : 17408) / 4;
  __shared__ float smem[SFLOATS];
  u16* patch = (u16*)smem;
  float* s_ep = smem;

  const int tid = threadIdx.x;
  const int wv = tid >> 6, ln = tid & 63;
  const int r = ln & 15, kb = ln >> 4;
  const int tile = blockIdx.x, ocb = blockIdx.y, n = blockIdx.z;
  const int oy0 = (tile / WT) * 8, ox0 = (tile % WT) * 8;
  const int y0p = oy0 - padY, x0p = ox0 - padX;
  const bool border = (y0p < 0) | (x0p < 0) | (y0p + PH > H) | (x0p + PW > W);

  const int sp = ln >> 2;
  const int cs = (ln & 3) * 8;

  int aoff0[4], xb[4];
#pragma unroll
  for (int m = 0; m < 4; ++m) {
    int pos = m * 16 + r;
    int sy = pos >> 3, sx = pos & 7;
    aoff0[m] = (sy * PW + sx) * 32;
    xb[m] = x0p + sx;
  }

  f32x4 acc[4] = {};
  f32x4 acc2[4] = {};

  const long actNS = (long)H * W * Cin;
  const long tstep = (long)Cout * Cin;
  const u16* wrow = wgt + (long)(ocb * 64 + wv * 16 + r) * Cin + kb * 8;
  const u16* gact = act + (long)n * actNS;

  if (border) {
    for (int i = tid; i < 2 * BUFU / 8; i += 256)
      ((int4*)patch)[i] = make_int4(0, 0, 0, 0);
  }
  __syncthreads();

  auto stage = [&](int b, int c0) {
    u16* bb = patch + b * BUFU;
    for (int u = wv; u < NW * NU; u += 4) {
      int pl = u / NU, up = u - pl * NU;
      u16* dst = bb + pl * PLANE + up * 512;
      int p = up * 16 + sp;
      int py = p / PW, px = p - py * PW;
      int gy = y0p + py, gx = x0p + px;
      bool valid = (p < PPOS) & ((unsigned)gy < (unsigned)H) & ((unsigned)gx < (unsigned)W);
      if (valid) {
        const u16* src = gact + pl * actPS + ((long)gy * W + gx) * Cin + c0 + cs;
        __builtin_amdgcn_global_load_lds((const gu32*)src, (lu32*)dst, 16, 0, 0);
      }
    }
  };

  stage(0, 0);
  int buf = 0;
  for (int c0 = 0; c0 < Cin; c0 += 32) {
    __syncthreads();
    s16x8 Bb[2][NW];
    {
      const u16* base = wrow + c0;
#pragma unroll
      for (int p = 0; p < NW; ++p) Bb[0][p] = *(const s16x8*)(base + p * wgtPS);
    }
    if (c0 + 32 < Cin) stage(buf ^ 1, c0 + 32);
    const u16* pb = patch + buf * BUFU;
#pragma unroll
    for (int t = 0; t < TAPS; ++t) {
      if (t + 1 < TAPS) {
        const u16* base = wrow + (long)(t + 1) * tstep + c0;
#pragma unroll
        for (int p = 0; p < NW; ++p)
          Bb[(t + 1) & 1][p] = *(const s16x8*)(base + p * wgtPS);
      }
      const int ky = t / KW, kx = t % KW;
#pragma unroll
      for (int m = 0; m < 4; ++m) {
        const int key = (xb[m] + kx) & 3;
        const int aoff = aoff0[m] + (ky * PW + kx) * 32 + ((kb ^ key) * 8);
        s16x8 a[NW];
#pragma unroll
        for (int p = 0; p < NW; ++p)
          a[p] = *(const s16x8*)(pb + p * PLANE + aoff);
        acc[m] = __builtin_amdgcn_mfma_f32_16x16x32_bf16(a[0], Bb[t & 1][0], acc[m], 0, 0, 0);
        if constexpr (NW == 2) {
          acc[m] = __builtin_amdgcn_mfma_f32_16x16x32_bf16(a[1], Bb[t & 1][0], acc[m], 0, 0, 0);
          acc[m] = __builtin_amdgcn_mfma_f32_16x16x32_bf16(a[0], Bb[t & 1][1], acc[m], 0, 0, 0);
        } else {
          acc2[m] = __builtin_amdgcn_mfma_f32_16x16x32_bf16(a[1], Bb[t & 1][0], acc2[m], 0, 0, 0);
          acc2[m] = __builtin_amdgcn_mfma_f32_16x16x32_bf16(a[0], Bb[t & 1][1], acc2[m], 0, 0, 0);
          acc2[m] = __builtin_amdgcn_mfma_f32_16x16x32_bf16(a[2], Bb[t & 1][0], acc2[m], 0, 0, 0);
          acc2[m] = __builtin_amdgcn_mfma_f32_16x16x32_bf16(a[0], Bb[t & 1][2], acc2[m], 0, 0, 0);
          acc2[m] = __builtin_amdgcn_mfma_f32_16x16x32_bf16(a[1], Bb[t & 1][1], acc2[m], 0, 0, 0);
        }
      }
    }
    buf ^= 1;
  }

  __syncthreads();
  const float bsv = bias[ocb * 64 + wv * 16 + r];
#pragma unroll
  for (int m = 0; m < 4; ++m) {
    f32x4 v = acc[m];
#pragma unroll
    for (int j = 0; j < 4; ++j) {
      float x = v[j];
      if constexpr (NW == 3) x += acc2[m][j];
      x += bsv;
      if (ACT == 1) x = fmaxf(x, 0.f);
      v[j] = x;
    }
    *(f32x4*)&s_ep[(wv * 16 + r) * 68 + m * 16 + kb * 4] = v;
  }
  __syncthreads();
  for (int i = tid; i < 4096; i += 256) {
    int oc = i >> 6, p2 = i & 63;
    int syy = p2 >> 3, sxx = p2 & 7;
    long off = outBase + (long)n * outNS + (long)(ocb * 64 + oc) * outCS
             + (long)(oy0 + syy) * outYS + (long)(ox0 + sxx) * outXS;
    out[off] = s_ep[oc * 68 + p2];
  }
}

// ---------------- convT weight rearrange into 4 parity 2x2 convs ------------
__global__ void rearrange_convT(const float* __restrict__ w, float* __restrict__ wp,
                                int Cin, int Cout) {
  int total = 4*Cout*Cin*4;
  for (int idx = blockIdx.x*256 + threadIdx.x; idx < total; idx += gridDim.x*256) {
    int e = idx & 1, d = (idx >> 1) & 1;
    int r = idx >> 2;
    int ic = r % Cin; r /= Cin;
    int oc = r % Cout; int p = r / Cout;
    int py = p >> 1, px = p & 1;
    int ky = py ? (d ? 0 : 2) : (d ? 1 : 3);
    int kx = px ? (e ? 0 : 2) : (e ? 1 : 3);
    wp[idx] = w[((ic*Cout + oc)*4 + ky)*4 + kx];
  }
}

// ---------------- codebook squared norms ----------------
__global__ __launch_bounds__(256) void cb_norm(const float* __restrict__ cb,
                                               float* __restrict__ outn) {
  int row = blockIdx.x;
  float v = cb[(long)row*256 + threadIdx.x];
  v *= v;
  for (int off = 32; off; off >>= 1) v += __shfl_down(v, off, 64);
  __shared__ float sr[4];
  if ((threadIdx.x & 63) == 0) sr[threadIdx.x >> 6] = v;
  __syncthreads();
  if (threadIdx.x == 0) outn[row] = sr[0] + sr[1] + sr[2] + sr[3];
}

__global__ void zero4(float* __restrict__ p) {
  if (threadIdx.x < 4) p[threadIdx.x] = 0.f;
}

// -------- z (NCHW) -> token-major zt + fp32 residual + 3 bf16 planes -------
__global__ __launch_bounds__(256) void transpose_zt(const float* __restrict__ z,
                                                    float* __restrict__ zt,
                                                    float* __restrict__ res,
                                                    u16* __restrict__ resp) {
  __shared__ float t[32][33];
  int b = blockIdx.z, c0 = blockIdx.y*32, hw0 = blockIdx.x*32;
  for (int i = threadIdx.x; i < 1024; i += 256) {
    int cc = i >> 5, ww = i & 31;
    t[cc][ww] = z[((long)(b*256 + c0 + cc) << 12) + hw0 + ww];
  }
  __syncthreads();
  for (int i = threadIdx.x; i < 1024; i += 256) {
    int ww = i >> 5, cc = i & 31;
    float v = t[cc][ww];
    long o = ((long)(b*4096 + hw0 + ww) << 8) + c0 + cc;
    zt[o] = v; res[o] = v;
    u16 h = f2bf(v);
    float r1 = v - bf2f(h);
    u16 m = f2bf(r1);
    resp[o] = h;
    resp[16777216L + o] = m;
    resp[33554432L + o] = f2bf(r1 - bf2f(m));
  }
}

// ---------------- quantized = zt - residual, token-major -> NCHW ------------
__global__ __launch_bounds__(256) void make_quantized(const float* __restrict__ zt,
                                                      const float* __restrict__ res,
                                                      float* __restrict__ q) {
  __shared__ float t[32][33];
  int b = blockIdx.z, c0 = blockIdx.y*32, hw0 = blockIdx.x*32;
  for (int i = threadIdx.x; i < 1024; i += 256) {
    int tt = i >> 5, cc = i & 31;
    long o = ((long)(b*4096 + hw0 + tt) << 8) + c0 + cc;
    t[cc][tt] = zt[o] - res[o];
  }
  __syncthreads();
  for (int i = threadIdx.x; i < 1024; i += 256) {
    int cc = i >> 5, ww = i & 31;
    q[((long)(b*256 + c0 + cc) << 12) + hw0 + ww] = t[cc][ww];
  }
}

// ---------------- one residual-VQ level, MFMA (3-word split) ---------------
// Block = 64 tokens (4 waves x 16). A (tokens) register-resident full K=256
// (96 VGPR). B (codes) staged through LDS once per (chunk, ks) -- all 4 waves
// consume identical B -- double-buffered, global_load_lds with pre-swizzled
// source (read-side XOR unswizzle on kb). ~210 VGPR total: no spill at the
// (256,2) occupancy bound. Shuffle argmin, first-index ties; fused update.
template<bool WP>
__global__ __launch_bounds__(256, 2) void vq_mfma(
    const u16* __restrict__ cbp, const float* __restrict__ cb,
    const float* __restrict__ cbn,
    float* __restrict__ res, u16* __restrict__ resp,
    float* __restrict__ idx_out, float* __restrict__ loss_out)
{
  __shared__ u16  sB[2][6144];    // [buf][plane 3][code 64][k 32], k-swizzled
  __shared__ int   s_idx[64];
  __shared__ float s_ls[4];
  const int tid = threadIdx.x;
  const int wv = tid >> 6, ln = tid & 63;
  const int r = ln & 15, kb = ln >> 4;
  const long t0 = (long)blockIdx.x * 64;
  const long tok = t0 + wv * 16 + r;

  // A fragments: 3 planes x 8 k-steps, register-resident (96 VGPR)
  s16x8 A[3][8];
#pragma unroll
  for (int p = 0; p < 3; ++p)
#pragma unroll
    for (int ks = 0; ks < 8; ++ks)
      A[p][ks] = *(const s16x8*)(resp + (long)p * 16777216 + tok * 256 + ks * 32 + kb * 8);

  // stage B tile (64 codes x 32 k x 3 planes = 12KB) for (n0, ks) into sB[b].
  // Source pre-swizzled so LDS holds [row][k ^ ((row&3)*8)] -> conflict-min
  // reads. 3 global_load_lds per wave, wave-uniform dst.
  const int srr = ln >> 2;                       // staging code sub-row 0..15
  const int sks = ((ln & 3) ^ (srr & 3)) * 8;    // staging swizzled k-offset
  auto stageB = [&](int b, int n0, int ks) {
    const int c0 = ks * 32;
#pragma unroll
    for (int i = 0; i < 3; ++i) {
      int u = wv + 4 * i;                        // 0..11
      int p = u >> 2, g = u & 3;
      const u16* src = cbp + (long)p * 262144
                     + (long)(n0 + g * 16 + srr) * 256 + c0 + sks;
      u16* dst = (u16*)&sB[b][p * 2048 + g * 512];
      __builtin_amdgcn_global_load_lds((const gu32*)src, (lu32*)dst, 16, 0, 0);
    }
  };

  float bv[4]; int bi[4];
#pragma unroll
  for (int j = 0; j < 4; ++j) { bv[j] = 3.4e38f; bi[j] = 0; }

  const int swk = (kb ^ (r & 3)) * 8;            // read-side unswizzle
  stageB(0, 0, 0);
  int buf = 0;
  for (int n0 = 0; n0 < 1024; n0 += 64) {
    f32x4 acc[4] = {};
    f32x4 acc2[4] = {};
#pragma unroll
    for (int ks = 0; ks < 8; ++ks) {
      __syncthreads();                           // sB[buf] ready (vmcnt drain)
      if (ks < 7)             stageB(buf ^ 1, n0, ks + 1);
      else if (n0 + 64 < 1024) stageB(buf ^ 1, n0 + 64, 0);
#pragma unroll
      for (int nt = 0; nt < 4; ++nt) {
        const u16* bb = &sB[buf][(nt * 16 + r) * 32 + swk];
        s16x8 b0 = *(const s16x8*)(bb);
        s16x8 b1 = *(const s16x8*)(bb + 2048);
        s16x8 b2 = *(const s16x8*)(bb + 4096);
        acc[nt]  = __builtin_amdgcn_mfma_f32_16x16x32_bf16(A[0][ks], b0, acc[nt], 0, 0, 0);
        acc2[nt] = __builtin_amdgcn_mfma_f32_16x16x32_bf16(A[1][ks], b0, acc2[nt], 0, 0, 0);
        acc2[nt] = __builtin_amdgcn_mfma_f32_16x16x32_bf16(A[0][ks], b1, acc2[nt], 0, 0, 0);
        acc2[nt] = __builtin_amdgcn_mfma_f32_16x16x32_bf16(A[2][ks], b0, acc2[nt], 0, 0, 0);
        acc2[nt] = __builtin_amdgcn_mfma_f32_16x16x32_bf16(A[0][ks], b2, acc2[nt], 0, 0, 0);
        acc2[nt] = __builtin_amdgcn_mfma_f32_16x16x32_bf16(A[1][ks], b1, acc2[nt], 0, 0, 0);
      }
      buf ^= 1;
    }
    // D: col(lane&15)=code-in-tile, row(kb*4+j)=token-in-M-tile
#pragma unroll
    for (int nt = 0; nt < 4; ++nt) {
      int code = n0 + nt * 16 + r;
      float cn = cbn[code];
#pragma unroll
      for (int j = 0; j < 4; ++j) {
        float d = cn - 2.f * (acc[nt][j] + acc2[nt][j]);
        if (d < bv[j]) { bv[j] = d; bi[j] = code; }   // ascending codes: strict <
      }
    }
  }

  // cross-lane argmin over the 16 code-columns (first-index ties)
#pragma unroll
  for (int m = 1; m < 16; m <<= 1) {
#pragma unroll
    for (int j = 0; j < 4; ++j) {
      float ov = __shfl_xor(bv[j], m, 64);
      int   oi = __shfl_xor(bi[j], m, 64);
      if (ov < bv[j] || (ov == bv[j] && oi < bi[j])) { bv[j] = ov; bi[j] = oi; }
    }
  }
  if (r == 0) {
#pragma unroll
    for (int j = 0; j < 4; ++j) s_idx[wv * 16 + kb * 4 + j] = bi[j];
  }
  __syncthreads();

  // fused update: thread tid = channel c; loop tokens
  const int c = tid;
  float lsum = 0.f;
  for (int m2 = 0; m2 < 64; ++m2) {
    int w = s_idx[m2];
    long ro = (t0 + m2) * 256 + c;
    float nv = res[ro] - cb[(long)w * 256 + c];
    res[ro] = nv;
    lsum += nv * nv;
    if (WP) {
      u16 h = f2bf(nv);
      float r1 = nv - bf2f(h);
      u16 mm = f2bf(r1);
      resp[ro] = h;
      resp[16777216L + ro] = mm;
      resp[33554432L + ro] = f2bf(r1 - bf2f(mm));
    }
  }
  for (int off = 32; off; off >>= 1) lsum += __shfl_down(lsum, off, 64);
  if (ln == 0) s_ls[wv] = lsum;
  __syncthreads();
  if (tid == 0)
    atomicAdd(loss_out, (s_ls[0] + s_ls[1] + s_ls[2] + s_ls[3]) * (1.f/(65536.f*256.f)));
  if (tid < 64) {
    long tglob = t0 + tid;
    int b = (int)(tglob >> 12), hw = (int)(tglob & 4095);
    idx_out[(long)b * 16384 + hw] = (float)s_idx[tid];
  }
}

// ---------------------------------------------------------------------------
extern "C" void kernel_launch(void* const* d_in, const int* in_sizes, int n_in,
                              void* d_out, int out_size, void* d_ws, size_t ws_size,
                              hipStream_t stream) {
  const float* x      = (const float*)d_in[0];
  const float* ew1    = (const float*)d_in[1];
  const float* eb1    = (const float*)d_in[2];
  const float* ew2    = (const float*)d_in[3];
  const float* eb2    = (const float*)d_in[4];
  const float* ew3    = (const float*)d_in[5];
  const float* eb3    = (const float*)d_in[6];
  const float* ew4    = (const float*)d_in[7];
  const float* eb4    = (const float*)d_in[8];
  const float* cbooks = (const float*)d_in[9];
  const float* dw1    = (const float*)d_in[10];
  const float* db1    = (const float*)d_in[11];
  const float* dw2    = (const float*)d_in[12];
  const float* db2    = (const float*)d_in[13];
  const float* dw3    = (const float*)d_in[14];
  const float* db3    = (const float*)d_in[15];
  const float* dw4    = (const float*)d_in[16];
  const float* db4    = (const float*)d_in[17];

  float* out = (float*)d_out;
  float* o_recon = out;                  // (16,3,512,512)
  float* o_idx   = out + 12582912;       // (16,4,64,64)
  float* o_loss  = out + 12845056;       // (4,)
  float* o_q     = out + 12845060;       // (16,256,64,64)

  float* ws  = (float*)d_ws;
  // fp32 prep region
  float* wp2 = ws;                        // 131072
  float* wp3 = ws + 131072;               //  65536
  float* wp4 = ws + 196608;               //   3072
  float* cbn = ws + 199680;               //   4096
  // bf16 weight planes (u16), base at float offset 203776
  u16* wu   = (u16*)(ws + 203776);
  u16* e3w  = wu;                         // 3 x 294912
  u16* e4w  = wu + 884736;                // 3 x 589824
  u16* d1w  = wu + 2654208;               // 2 x 294912
  u16* t2w  = wu + 3244032;               // 4 x (2 x 32768)
  u16* t3w  = wu + 3506176;               // 4 x (2 x 16384) -> ends 3637248

  const long DA = 2097152;
  float* h1  = ws + DA;
  float* h2  = ws + DA + 16777216;
  float* h3  = ws + DA;                   // h1 dead
  float* z   = ws + DA + 58720256;        // 16,777,216
  float* zt  = ws + DA;                   // h3 dead
  float* res = ws + DA + 16777216;        // A4 dead
  u16* resp  = (u16*)(ws + DA + 33554432);// 3 x 16,777,216 u16
  u16* cbp   = (u16*)(ws + DA + 75497472);// 4 x 786,432 u16 (dead before d3)
  float* d1  = ws + DA;                   // zt dead
  float* d2  = ws + DA + 16777216;        // res dead
  float* d3  = ws + DA + 16777216;        // D3 consumed
  u16* A3 = (u16*)(ws + DA + 25165824);   // 3 x 8,388,608 u16
  u16* A4 = (u16*)(ws + DA + 16777216);   // 3 x 16,777,216 u16
  u16* D1 = (u16*)(ws + DA + 33554432);   // 2 x 16,777,216 u16 (resp dead)
  u16* D2 = (u16*)(ws + DA + 8388608);    // 2 x 8,388,608 u16
  u16* D3 = (u16*)(ws + DA);              // 2 x 16,777,216 u16

  // ---------------- prep ----------------
  rearrange_convT<<<256, 256, 0, stream>>>(dw2, wp2, 128, 64);
  rearrange_convT<<<256, 256, 0, stream>>>(dw3, wp3, 64, 64);
  rearrange_convT<<<16, 256, 0, stream>>>(dw4, wp4, 64, 3);
  cb_norm<<<4096, 256, 0, stream>>>(cbooks, cbn);
  cbsplit<<<512, 256, 0, stream>>>(cbooks, cbp);
  zero4<<<1, 64, 0, stream>>>(o_loss);
  wsplit<3><<<256, 256, 0, stream>>>(ew3, e3w, 294912L, 256, 128, 9);
  wsplit<3><<<256, 256, 0, stream>>>(ew4, e4w, 589824L, 256, 256, 9);
  wsplit<2><<<256, 256, 0, stream>>>(dw1, d1w, 294912L, 128, 256, 9);
  for (int p = 0; p < 4; ++p) {
    wsplit<2><<<64, 256, 0, stream>>>(wp2 + p*32768, t2w + p*65536, 32768L, 64, 128, 4);
    wsplit<2><<<64, 256, 0, stream>>>(wp3 + p*16384, t3w + p*32768, 16384L, 64, 64, 4);
  }

  // ---------------- encoder ----------------
  conv_tiled<64,8,8,4,4,2,1><<<dim3(256,1,16), 256, 0, stream>>>(
      x, ew1, eb1, h1, 16, 3, 256, 256, 64, 16, 1, 1,
      0L, 1048576L, 16384L, 128L, 1L);
  conv_tiled<64,8,8,4,4,2,1><<<dim3(64,2,16), 256, 0, stream>>>(
      h1, ew2, eb2, h2, 16, 64, 128, 128, 128, 8, 1, 1,
      0L, 524288L, 4096L, 64L, 1L);

  to_nhwc_bf16<3><<<dim3(64,4,16), 256, 0, stream>>>(h2, A3, 8388608L, 128, 4096);
  conv_mfma<3,3,1,3><<<dim3(64,4,16), 256, 0, stream>>>(
      A3, 8388608L, e3w, 294912L, eb3, h3,
      128, 64, 64, 256, 8, 1, 1, 0L, 1048576L, 4096L, 64L, 1L);

  to_nhwc_bf16<3><<<dim3(64,8,16), 256, 0, stream>>>(h3, A4, 16777216L, 256, 4096);
  conv_mfma<3,3,0,3><<<dim3(64,4,16), 256, 0, stream>>>(
      A4, 16777216L, e4w, 589824L, eb4, z,
      256, 64, 64, 256, 8, 1, 1, 0L, 1048576L, 4096L, 64L, 1L);

  // ---------------- VQ ----------------
  transpose_zt<<<dim3(128,8,16), 256, 0, stream>>>(z, zt, res, resp);
  for (int l = 0; l < 3; ++l)
    vq_mfma<true><<<1024, 256, 0, stream>>>(cbp + (long)l*786432,
        cbooks + (long)l*262144, cbn + l*1024, res, resp,
        o_idx + l*4096, o_loss + l);
  vq_mfma<false><<<1024, 256, 0, stream>>>(cbp + 3L*786432,
      cbooks + 3L*262144, cbn + 3*1024, res, resp,
      o_idx + 3*4096, o_loss + 3);
  make_quantized<<<dim3(128,8,16), 256, 0, stream>>>(zt, res, o_q);

  // ---------------- decoder ----------------
  to_nhwc_bf16<2><<<dim3(64,8,16), 256, 0, stream>>>(o_q, D1, 16777216L, 256, 4096);
  conv_mfma<3,3,1,2><<<dim3(64,2,16), 256, 0, stream>>>(
      D1, 16777216L, d1w, 294912L, db1, d1,
      256, 64, 64, 128, 8, 1, 1, 0L, 524288L, 4096L, 64L, 1L);

  to_nhwc_bf16<2><<<dim3(64,4,16), 256, 0, stream>>>(d1, D2, 8388608L, 128, 4096);
  for (int p = 0; p < 4; ++p) {
    int py = p >> 1, px = p & 1;
    conv_mfma<2,2,1,2><<<dim3(64,1,16), 256, 0, stream>>>(
        D2, 8388608L, t2w + p*65536, 32768L, db2, d2,
        128, 64, 64, 64, 8, 1-py, 1-px,
        (long)(py*128 + px), 1048576L, 16384L, 256L, 2L);
  }

  to_nhwc_bf16<2><<<dim3(256,2,16), 256, 0, stream>>>(d2, D3, 16777216L, 64, 16384);
  for (int p = 0; p < 4; ++p) {
    int py = p >> 1, px = p & 1;
    conv_mfma<2,2,1,2><<<dim3(256,1,16), 256, 0, stream>>>(
        D3, 16777216L, t3w + p*32768, 16384L, db3, d3,
        64, 128, 128, 64, 16, 1-py, 1-px,
        (long)(py*256 + px), 4194304L, 65536L, 512L, 2L);
  }

  for (int p = 0; p < 4; ++p) {
    int py = p >> 1, px = p & 1;
    conv_tiled<4,16,16,2,2,1,2><<<dim3(256,1,16), 256, 0, stream>>>(
        d3, wp4 + p*768, db4, o_recon, 16, 64, 256, 256, 3, 16, 1-py, 1-px,
        (long)(py*512 + px), 786432L, 262144L, 1024L, 2L);
  }
  (void)in_sizes; (void)n_in; (void)out_size; (void)ws_size;
}

// Round 7
// 3651.344 us; speedup vs baseline: 1.7721x; 1.1343x over previous
//
#include <hip/hip_runtime.h>
#include <cmath>

// ---------------------------------------------------------------------------
// RQ-VAE forward, round 7.
// enc1/enc2 (stride-2 4x4 convs) converted to MFMA via parity decomposition:
// stride-2 4x4 conv == stride-1 2x2 conv over 4 parity planes stacked as
// channels (ky=2d+ry, kx=2e+rx; odd planes row-shifted so all parities share
// the window; border zeros baked into the planes). Reuses conv_mfma<2,2,1,3>
// unchanged. New par_nhwc (parity-NHWC 3-word builder) + wsplit_s2.
// Everything else identical to passing round 6.
// ---------------------------------------------------------------------------

typedef unsigned short u16;
typedef unsigned int   u32;
typedef __attribute__((ext_vector_type(8))) short s16x8;
typedef __attribute__((ext_vector_type(4))) short s16x4;
typedef __attribute__((ext_vector_type(4))) float f32x4;
typedef __attribute__((address_space(1))) const u32 gu32;
typedef __attribute__((address_space(3))) u32 lu32;

__device__ __forceinline__ u16 f2bf(float v) {   // RNE fp32->bf16 bits
  u32 b = __builtin_bit_cast(u32, v);
  b += 0x7FFFu + ((b >> 16) & 1u);
  return (u16)(b >> 16);
}
__device__ __forceinline__ float bf2f(u16 h) {
  u32 b = ((u32)h) << 16;
  return __builtin_bit_cast(float, b);
}

// ---------------- row vector load from LDS (aligned) ----------------
template<int RW>
__device__ __forceinline__ void load_row(const float* __restrict__ p, float* r) {
  if constexpr (RW == 5) {
    float4 a = *(const float4*)p;
    r[0]=a.x; r[1]=a.y; r[2]=a.z; r[3]=a.w; r[4]=p[4];
  } else if constexpr (RW == 6) {
    float4 a = *(const float4*)p; float2 b = *(const float2*)(p+4);
    r[0]=a.x; r[1]=a.y; r[2]=a.z; r[3]=a.w; r[4]=b.x; r[5]=b.y;
  } else if constexpr (RW == 10) {
    float4 a = *(const float4*)p; float4 b = *(const float4*)(p+4);
    float2 c = *(const float2*)(p+8);
    r[0]=a.x; r[1]=a.y; r[2]=a.z; r[3]=a.w;
    r[4]=b.x; r[5]=b.y; r[6]=b.z; r[7]=b.w; r[8]=c.x; r[9]=c.y;
  }
}

// ---------------- generic tiled direct conv (fp32, head only now) ----------
template<int OCT, int SPTH, int SPTW, int KH, int KW, int S, int ACT>
__global__ __launch_bounds__(256) void conv_tiled(
    const float* __restrict__ in, const float* __restrict__ wgt,
    const float* __restrict__ bias, float* __restrict__ out,
    int N, int Cin, int Hin, int Win, int Cout, int WT,
    int padY, int padX,
    long outBase, long outNStride, long outCStride, long outYStride, long outXStride)
{
  constexpr int CK   = 8;
  constexpr int IH   = (SPTH-1)*S + KH;
  constexpr int IWr  = (SPTW-1)*S + KW;
  constexpr int IW   = (IWr + 3) & ~3;
  constexpr int TAPS = KH*KW;
  constexpr int WST  = (OCT==64) ? 68 : 5;
  constexpr int LOC  = (OCT==64) ? 16 : 4;
  constexpr int OPT  = OCT/LOC;
  constexpr int RW   = 3*S + KW;
  constexpr int EPW  = (OCT==64) ? 65 : 257;
  constexpr int SP   = SPTH*SPTW;
  constexpr int STG  = CK*IH*IW + CK*TAPS*WST;
  constexpr int SMEMN = (STG > OCT*EPW) ? STG : OCT*EPW;
  __shared__ float smem[SMEMN];
  float* s_in = smem;
  float* s_w  = smem + CK*IH*IW;

  const int tid  = threadIdx.x;
  const int tile = blockIdx.x, ocb = blockIdx.y, n = blockIdx.z;
  const int oy0 = (tile / WT) * SPTH, ox0 = (tile % WT) * SPTW;
  const int ol  = tid % LOC;
  const int g   = tid / LOC;
  const int s0  = g * 4;
  const int sy  = s0 / SPTW, sx0 = s0 % SPTW;
  const int iy0 = oy0*S - padY, ix0 = ox0*S - padX;

  float acc[OPT][4];
#pragma unroll
  for (int o = 0; o < OPT; ++o)
#pragma unroll
    for (int j = 0; j < 4; ++j) acc[o][j] = 0.f;

  for (int c0 = 0; c0 < Cin; c0 += CK) {
    __syncthreads();
    for (int i = tid; i < CK*IH*IW; i += 256) {
      int c = i / (IH*IW), r2 = i % (IH*IW);
      int iy = r2 / IW, ix = r2 % IW;
      int gy = iy0 + iy, gx = ix0 + ix;
      float v = 0.f;
      if (c0 + c < Cin && (unsigned)gy < (unsigned)Hin && (unsigned)gx < (unsigned)Win)
        v = in[(((long)n*Cin + c0 + c)*Hin + gy)*Win + gx];
      s_in[i] = v;
    }
    for (int i = tid; i < OCT*CK*TAPS; i += 256) {
      int o = i / (CK*TAPS), ct = i % (CK*TAPS);
      int oc = ocb*OCT + o, ci = c0 + ct / TAPS;
      float v = 0.f;
      if (oc < Cout && ci < Cin)
        v = wgt[((long)oc*Cin + ci)*TAPS + (ct % TAPS)];
      s_w[ct*WST + o] = v;
    }
    __syncthreads();

    for (int c = 0; c < CK; ++c) {
#pragma unroll
      for (int ky = 0; ky < KH; ++ky) {
        float r[RW];
        load_row<RW>(&s_in[c*(IH*IW) + (sy*S + ky)*IW + sx0*S], r);
#pragma unroll
        for (int kx = 0; kx < KW; ++kx) {
          if constexpr (OCT == 64) {
            float4 w4 = *(const float4*)&s_w[(c*TAPS + ky*KW + kx)*WST + ol*4];
            float wv[4] = {w4.x, w4.y, w4.z, w4.w};
#pragma unroll
            for (int o = 0; o < 4; ++o)
#pragma unroll
              for (int j = 0; j < 4; ++j)
                acc[o][j] = fmaf(wv[o], r[j*S + kx], acc[o][j]);
          } else {
            float w = s_w[(c*TAPS + ky*KW + kx)*WST + ol];
#pragma unroll
            for (int j = 0; j < 4; ++j)
              acc[0][j] = fmaf(w, r[j*S + kx], acc[0][j]);
          }
        }
      }
    }
  }

  __syncthreads();
#pragma unroll
  for (int o = 0; o < OPT; ++o) {
    int oc = ocb*OCT + ol*OPT + o;
    float b = (oc < Cout) ? bias[oc] : 0.f;
#pragma unroll
    for (int j = 0; j < 4; ++j) {
      float v = acc[o][j] + b;
      if constexpr (ACT == 1) v = fmaxf(v, 0.f);
      else if constexpr (ACT == 2) v = tanhf(v);
      smem[(ol*OPT + o)*EPW + s0 + j] = v;
    }
  }
  __syncthreads();
  for (int i = tid; i < OCT*SP; i += 256) {
    int o = i / SP, sp = i % SP;
    int oc = ocb*OCT + o;
    if (oc < Cout) {
      int syy = sp / SPTW, sxx = sp % SPTW;
      long off = outBase + (long)n*outNStride + (long)oc*outCStride
               + (long)(oy0 + syy)*outYStride + (long)(ox0 + sxx)*outXStride;
      out[off] = smem[o*EPW + sp];
    }
  }
}

// ---------------- NCHW fp32 -> NHWC bf16 planes (swizzled), NP words -------
template<int NP>
__global__ __launch_bounds__(256) void to_nhwc_bf16(const float* __restrict__ in,
    u16* __restrict__ t, long PS, int C, int HW) {
  __shared__ float sm[32][65];
  const int n = blockIdx.z, c0 = blockIdx.y << 5, w0 = blockIdx.x << 6;
  const long ibase = ((long)n * C + c0) * HW + w0;
  for (int i = threadIdx.x; i < 2048; i += 256) {
    int c = i >> 6, w = i & 63;
    sm[c][w] = in[ibase + (long)c * HW + w];
  }
  __syncthreads();
  for (int i = threadIdx.x; i < 512; i += 256) {
    int w = i >> 3, c4 = (i & 7) << 2;
    short hv[4], mv[4], lv[4];
#pragma unroll
    for (int q = 0; q < 4; ++q) {
      float v = sm[c4 + q][w];
      u16 h = f2bf(v); hv[q] = (short)h;
      float r1 = v - bf2f(h);
      u16 m = f2bf(r1); mv[q] = (short)m;
      if (NP == 3) lv[q] = (short)f2bf(r1 - bf2f(m));
    }
    int scr = c4 ^ ((w & 3) << 3);
    long o = ((long)n * HW + w0 + w) * C + c0 + scr;
    *(s16x4*)(t + o)      = *(s16x4*)hv;
    *(s16x4*)(t + PS + o) = *(s16x4*)mv;
    if (NP == 3) *(s16x4*)(t + 2*PS + o) = *(s16x4*)lv;
  }
}

// -------- parity-NHWC builder: NCHW fp32 -> 3-word bf16 parity planes ------
// Plane: [n][u][v][C'=4*CBLK], HP x HP grid. g = ry*2+rx; ry/rx: 0 = odd
// source line (iy=2u-1 / ix=2v-1), 1 = even (iy=2u / ix=2v); out-of-range
// source -> 0. Channel slot within each 32-group: (cc&31) ^ ((v&3)<<3).
template<int C, int CBLK>
__global__ __launch_bounds__(256) void par_nhwc(
    const float* __restrict__ in, u16* __restrict__ t, long PS,
    int Hin, int Win, int HP)
{
  constexpr int CP = 4 * CBLK;
  constexpr int QPV = CP / 4;
  __shared__ float sm[2][C][66];
  const int n = blockIdx.z, u = blockIdx.y, v0 = blockIdx.x * 32;
  const long ib = (long)n * C * Hin * Win;
  for (int i = threadIdx.x; i < 2 * C * 66; i += 256) {
    int j = i % 66; int c = (i / 66) % C; int rr = i / (66 * C);
    int gy = rr ? 2 * u : 2 * u - 1;
    int gx = 2 * v0 - 1 + j;
    float val = 0.f;
    if ((unsigned)gy < (unsigned)Hin && (unsigned)gx < (unsigned)Win)
      val = in[ib + ((long)c * Hin + gy) * Win + gx];
    sm[rr][c][j] = val;
  }
  __syncthreads();
  for (int q = threadIdx.x; q < 32 * QPV; q += 256) {
    int v = v0 + q / QPV;
    if (v >= HP) continue;
    int cq = (q % QPV) * 4;
    int g = cq / CBLK, cb = cq % CBLK;
    int ry = g >> 1, rx = g & 1;
    int j = 2 * (v - v0) + rx;
    short hv[4], mv[4], lv[4];
#pragma unroll
    for (int p = 0; p < 4; ++p) {
      int c = cb + p;
      float val = (c < C) ? sm[ry][c][j] : 0.f;
      u16 h = f2bf(val); hv[p] = (short)h;
      float r1 = val - bf2f(h);
      u16 m = f2bf(r1); mv[p] = (short)m;
      lv[p] = (short)f2bf(r1 - bf2f(m));
    }
    int cc = g * CBLK + cb;
    int grp = cc >> 5;
    int slot = (cc & 31) ^ ((v & 3) << 3);
    long o = (((long)n * HP + u) * HP + v) * CP + (grp << 5) + slot;
    *(s16x4*)(t + o)        = *(s16x4*)hv;
    *(s16x4*)(t + PS + o)   = *(s16x4*)mv;
    *(s16x4*)(t + 2*PS + o) = *(s16x4*)lv;
  }
}

// ---------------- weight split: [oc][ic][tap] fp32 -> NP x [tap][oc][ic] ---
template<int NP>
__global__ void wsplit(const float* __restrict__ w, u16* __restrict__ dst,
                       long PS, int Cout, int Cin, int TAPS) {
  int total = TAPS * Cout * Cin;
  for (int i = blockIdx.x * 256 + threadIdx.x; i < total; i += gridDim.x * 256) {
    int ic = i % Cin; int rest = i / Cin; int oc = rest % Cout; int tap = rest / Cout;
    float v = w[((long)oc * Cin + ic) * TAPS + tap];
    u16 h = f2bf(v);
    dst[i] = h;
    float r1 = v - bf2f(h);
    u16 m = f2bf(r1);
    dst[PS + i] = m;
    if (NP == 3) dst[2*PS + i] = f2bf(r1 - bf2f(m));
  }
}

// -------- stride-2 4x4 weights -> parity 2x2 weights, 3-word, [t][oc][cc'] -
template<int C, int CBLK>
__global__ void wsplit_s2(const float* __restrict__ w, u16* __restrict__ dst,
                          long PS, int Cout) {
  constexpr int CP = 4 * CBLK;
  int total = 4 * Cout * CP;
  for (int i = blockIdx.x * 256 + threadIdx.x; i < total; i += gridDim.x * 256) {
    int cc = i % CP; int oc = (i / CP) % Cout; int t = i / (CP * Cout);
    int d = t >> 1, e = t & 1;
    int g = cc / CBLK, c = cc % CBLK;
    int ry = g >> 1, rx = g & 1;
    int ky = 2 * d + ry, kx = 2 * e + rx;
    float v = (c < C) ? w[((long)(oc * C + c) * 4 + ky) * 4 + kx] : 0.f;
    u16 h = f2bf(v); dst[i] = h;
    float r1 = v - bf2f(h);
    u16 m = f2bf(r1); dst[PS + i] = m;
    dst[2*PS + i] = f2bf(r1 - bf2f(m));
  }
}

// ---------------- codebook split: 4x[1024][256] fp32 -> per-level 3 planes --
__global__ void cbsplit(const float* __restrict__ cb, u16* __restrict__ dst) {
  int total = 4 * 1024 * 256;
  for (int i = blockIdx.x * 256 + threadIdx.x; i < total; i += gridDim.x * 256) {
    int l = i >> 18, kc = i & 262143;
    float v = cb[i];
    u16 h = f2bf(v);
    float r1 = v - bf2f(h);
    u16 m = f2bf(r1);
    long b = (long)l * 786432 + kc;
    dst[b] = h;
    dst[b + 262144] = m;
    dst[b + 524288] = f2bf(r1 - bf2f(m));
  }
}

// ---------------- MFMA conv: 8x8 spatial x 64 oc, NW-word bf16 -------------
template<int KH, int KW, int ACT, int NW>
__global__ __launch_bounds__(256, 3) void conv_mfma(
    const u16* __restrict__ act, long actPS,
    const u16* __restrict__ wgt, long wgtPS,
    const float* __restrict__ bias, float* __restrict__ out,
    int Cin, int H, int W, int Cout, int WT, int padY, int padX,
    long outBase, long outNS, long outCS, long outYS, long outXS)
{
  constexpr int PH = 8 + KH - 1, PW = 8 + KW - 1;
  constexpr int PPOS = PH * PW;
  constexpr int NU = (PPOS + 15) / 16;
  constexpr int PLANE = NU * 512;
  constexpr int BUFU = NW * PLANE;
  constexpr int TAPS = KH * KW;
  constexpr int PATCHB = 2 * BUFU * 2;
  constexpr int SFLOATS = ((PATCHB > 17408) ? PATCHB : 17408) / 4;
  __shared__ float smem[SFLOATS];
  u16* patch = (u16*)smem;
  float* s_ep = smem;

  const int tid = threadIdx.x;
  const int wv = tid >> 6, ln = tid & 63;
  const int r = ln & 15, kb = ln >> 4;
  const int tile = blockIdx.x, ocb = blockIdx.y, n = blockIdx.z;
  const int oy0 = (tile / WT) * 8, ox0 = (tile % WT) * 8;
  const int y0p = oy0 - padY, x0p = ox0 - padX;
  const bool border = (y0p < 0) | (x0p < 0) | (y0p + PH > H) | (x0p + PW > W);

  const int sp = ln >> 2;
  const int cs = (ln & 3) * 8;

  int aoff0[4], xb[4];
#pragma unroll
  for (int m = 0; m < 4; ++m) {
    int pos = m * 16 + r;
    int sy = pos >> 3, sx = pos & 7;
    aoff0[m] = (sy * PW + sx) * 32;
    xb[m] = x0p + sx;
  }

  f32x4 acc[4] = {};
  f32x4 acc2[4] = {};

  const long actNS = (long)H * W * Cin;
  const long tstep = (long)Cout * Cin;
  const u16* wrow = wgt + (long)(ocb * 64 + wv * 16 + r) * Cin + kb * 8;
  const u16* gact = act + (long)n * actNS;

  if (border) {
    for (int i = tid; i < 2 * BUFU / 8; i += 256)
      ((int4*)patch)[i] = make_int4(0, 0, 0, 0);
  }
  __syncthreads();

  auto stage = [&](int b, int c0) {
    u16* bb = patch + b * BUFU;
    for (int u = wv; u < NW * NU; u += 4) {
      int pl = u / NU, up = u - pl * NU;
      u16* dst = bb + pl * PLANE + up * 512;
      int p = up * 16 + sp;
      int py = p / PW, px = p - py * PW;
      int gy = y0p + py, gx = x0p + px;
      bool valid = (p < PPOS) & ((unsigned)gy < (unsigned)H) & ((unsigned)gx < (unsigned)W);
      if (valid) {
        const u16* src = gact + pl * actPS + ((long)gy * W + gx) * Cin + c0 + cs;
        __builtin_amdgcn_global_load_lds((const gu32*)src, (lu32*)dst, 16, 0, 0);
      }
    }
  };

  stage(0, 0);
  int buf = 0;
  for (int c0 = 0; c0 < Cin; c0 += 32) {
    __syncthreads();
    s16x8 Bb[2][NW];
    {
      const u16* base = wrow + c0;
#pragma unroll
      for (int p = 0; p < NW; ++p) Bb[0][p] = *(const s16x8*)(base + p * wgtPS);
    }
    if (c0 + 32 < Cin) stage(buf ^ 1, c0 + 32);
    const u16* pb = patch + buf * BUFU;
#pragma unroll
    for (int t = 0; t < TAPS; ++t) {
      if (t + 1 < TAPS) {
        const u16* base = wrow + (long)(t + 1) * tstep + c0;
#pragma unroll
        for (int p = 0; p < NW; ++p)
          Bb[(t + 1) & 1][p] = *(const s16x8*)(base + p * wgtPS);
      }
      const int ky = t / KW, kx = t % KW;
#pragma unroll
      for (int m = 0; m < 4; ++m) {
        const int key = (xb[m] + kx) & 3;
        const int aoff = aoff0[m] + (ky * PW + kx) * 32 + ((kb ^ key) * 8);
        s16x8 a[NW];
#pragma unroll
        for (int p = 0; p < NW; ++p)
          a[p] = *(const s16x8*)(pb + p * PLANE + aoff);
        acc[m] = __builtin_amdgcn_mfma_f32_16x16x32_bf16(a[0], Bb[t & 1][0], acc[m], 0, 0, 0);
        if constexpr (NW == 2) {
          acc[m] = __builtin_amdgcn_mfma_f32_16x16x32_bf16(a[1], Bb[t & 1][0], acc[m], 0, 0, 0);
          acc[m] = __builtin_amdgcn_mfma_f32_16x16x32_bf16(a[0], Bb[t & 1][1], acc[m], 0, 0, 0);
        } else {
          acc2[m] = __builtin_amdgcn_mfma_f32_16x16x32_bf16(a[1], Bb[t & 1][0], acc2[m], 0, 0, 0);
          acc2[m] = __builtin_amdgcn_mfma_f32_16x16x32_bf16(a[0], Bb[t & 1][1], acc2[m], 0, 0, 0);
          acc2[m] = __builtin_amdgcn_mfma_f32_16x16x32_bf16(a[2], Bb[t & 1][0], acc2[m], 0, 0, 0);
          acc2[m] = __builtin_amdgcn_mfma_f32_16x16x32_bf16(a[0], Bb[t & 1][2], acc2[m], 0, 0, 0);
          acc2[m] = __builtin_amdgcn_mfma_f32_16x16x32_bf16(a[1], Bb[t & 1][1], acc2[m], 0, 0, 0);
        }
      }
    }
    buf ^= 1;
  }

  __syncthreads();
  const float bsv = bias[ocb * 64 + wv * 16 + r];
#pragma unroll
  for (int m = 0; m < 4; ++m) {
    f32x4 v = acc[m];
#pragma unroll
    for (int j = 0; j < 4; ++j) {
      float x = v[j];
      if constexpr (NW == 3) x += acc2[m][j];
      x += bsv;
      if (ACT == 1) x = fmaxf(x, 0.f);
      v[j] = x;
    }
    *(f32x4*)&s_ep[(wv * 16 + r) * 68 + m * 16 + kb * 4] = v;
  }
  __syncthreads();
  for (int i = tid; i < 4096; i += 256) {
    int oc = i >> 6, p2 = i & 63;
    int syy = p2 >> 3, sxx = p2 & 7;
    long off = outBase + (long)n * outNS + (long)(ocb * 64 + oc) * outCS
             + (long)(oy0 + syy) * outYS + (long)(ox0 + sxx) * outXS;
    out[off] = s_ep[oc * 68 + p2];
  }
}

// ---------------- convT weight rearrange into 4 parity 2x2 convs ------------
__global__ void rearrange_convT(const float* __restrict__ w, float* __restrict__ wp,
                                int Cin, int Cout) {
  int total = 4*Cout*Cin*4;
  for (int idx = blockIdx.x*256 + threadIdx.x; idx < total; idx += gridDim.x*256) {
    int e = idx & 1, d = (idx >> 1) & 1;
    int r = idx >> 2;
    int ic = r % Cin; r /= Cin;
    int oc = r % Cout; int p = r / Cout;
    int py = p >> 1, px = p & 1;
    int ky = py ? (d ? 0 : 2) : (d ? 1 : 3);
    int kx = px ? (e ? 0 : 2) : (e ? 1 : 3);
    wp[idx] = w[((ic*Cout + oc)*4 + ky)*4 + kx];
  }
}

// ---------------- codebook squared norms ----------------
__global__ __launch_bounds__(256) void cb_norm(const float* __restrict__ cb,
                                               float* __restrict__ outn) {
  int row = blockIdx.x;
  float v = cb[(long)row*256 + threadIdx.x];
  v *= v;
  for (int off = 32; off; off >>= 1) v += __shfl_down(v, off, 64);
  __shared__ float sr[4];
  if ((threadIdx.x & 63) == 0) sr[threadIdx.x >> 6] = v;
  __syncthreads();
  if (threadIdx.x == 0) outn[row] = sr[0] + sr[1] + sr[2] + sr[3];
}

__global__ void zero4(float* __restrict__ p) {
  if (threadIdx.x < 4) p[threadIdx.x] = 0.f;
}

// -------- z (NCHW) -> token-major zt + fp32 residual + 3 bf16 planes -------
__global__ __launch_bounds__(256) void transpose_zt(const float* __restrict__ z,
                                                    float* __restrict__ zt,
                                                    float* __restrict__ res,
                                                    u16* __restrict__ resp) {
  __shared__ float t[32][33];
  int b = blockIdx.z, c0 = blockIdx.y*32, hw0 = blockIdx.x*32;
  for (int i = threadIdx.x; i < 1024; i += 256) {
    int cc = i >> 5, ww = i & 31;
    t[cc][ww] = z[((long)(b*256 + c0 + cc) << 12) + hw0 + ww];
  }
  __syncthreads();
  for (int i = threadIdx.x; i < 1024; i += 256) {
    int ww = i >> 5, cc = i & 31;
    float v = t[cc][ww];
    long o = ((long)(b*4096 + hw0 + ww) << 8) + c0 + cc;
    zt[o] = v; res[o] = v;
    u16 h = f2bf(v);
    float r1 = v - bf2f(h);
    u16 m = f2bf(r1);
    resp[o] = h;
    resp[16777216L + o] = m;
    resp[33554432L + o] = f2bf(r1 - bf2f(m));
  }
}

// ---------------- quantized = zt - residual, token-major -> NCHW ------------
__global__ __launch_bounds__(256) void make_quantized(const float* __restrict__ zt,
                                                      const float* __restrict__ res,
                                                      float* __restrict__ q) {
  __shared__ float t[32][33];
  int b = blockIdx.z, c0 = blockIdx.y*32, hw0 = blockIdx.x*32;
  for (int i = threadIdx.x; i < 1024; i += 256) {
    int tt = i >> 5, cc = i & 31;
    long o = ((long)(b*4096 + hw0 + tt) << 8) + c0 + cc;
    t[cc][tt] = zt[o] - res[o];
  }
  __syncthreads();
  for (int i = threadIdx.x; i < 1024; i += 256) {
    int cc = i >> 5, ww = i & 31;
    q[((long)(b*256 + c0 + cc) << 12) + hw0 + ww] = t[cc][ww];
  }
}

// ---------------- one residual-VQ level, MFMA (3-word split) ---------------
template<bool WP>
__global__ __launch_bounds__(256, 2) void vq_mfma(
    const u16* __restrict__ cbp, const float* __restrict__ cb,
    const float* __restrict__ cbn,
    float* __restrict__ res, u16* __restrict__ resp,
    float* __restrict__ idx_out, float* __restrict__ loss_out)
{
  __shared__ u16  sB[2][6144];
  __shared__ int   s_idx[64];
  __shared__ float s_ls[4];
  const int tid = threadIdx.x;
  const int wv = tid >> 6, ln = tid & 63;
  const int r = ln & 15, kb = ln >> 4;
  const long t0 = (long)blockIdx.x * 64;
  const long tok = t0 + wv * 16 + r;

  s16x8 A[3][8];
#pragma unroll
  for (int p = 0; p < 3; ++p)
#pragma unroll
    for (int ks = 0; ks < 8; ++ks)
      A[p][ks] = *(const s16x8*)(resp + (long)p * 16777216 + tok * 256 + ks * 32 + kb * 8);

  const int srr = ln >> 2;
  const int sks = ((ln & 3) ^ (srr & 3)) * 8;
  auto stageB = [&](int b, int n0, int ks) {
    const int c0 = ks * 32;
#pragma unroll
    for (int i = 0; i < 3; ++i) {
      int u = wv + 4 * i;
      int p = u >> 2, g = u & 3;
      const u16* src = cbp + (long)p * 262144
                     + (long)(n0 + g * 16 + srr) * 256 + c0 + sks;
      u16* dst = (u16*)&sB[b][p * 2048 + g * 512];
      __builtin_amdgcn_global_load_lds((const gu32*)src, (lu32*)dst, 16, 0, 0);
    }
  };

  float bv[4]; int bi[4];
#pragma unroll
  for (int j = 0; j < 4; ++j) { bv[j] = 3.4e38f; bi[j] = 0; }

  const int swk = (kb ^ (r & 3)) * 8;
  stageB(0, 0, 0);
  int buf = 0;
  for (int n0 = 0; n0 < 1024; n0 += 64) {
    f32x4 acc[4] = {};
    f32x4 acc2[4] = {};
#pragma unroll
    for (int ks = 0; ks < 8; ++ks) {
      __syncthreads();
      if (ks < 7)             stageB(buf ^ 1, n0, ks + 1);
      else if (n0 + 64 < 1024) stageB(buf ^ 1, n0 + 64, 0);
#pragma unroll
      for (int nt = 0; nt < 4; ++nt) {
        const u16* bb = &sB[buf][(nt * 16 + r) * 32 + swk];
        s16x8 b0 = *(const s16x8*)(bb);
        s16x8 b1 = *(const s16x8*)(bb + 2048);
        s16x8 b2 = *(const s16x8*)(bb + 4096);
        acc[nt]  = __builtin_amdgcn_mfma_f32_16x16x32_bf16(A[0][ks], b0, acc[nt], 0, 0, 0);
        acc2[nt] = __builtin_amdgcn_mfma_f32_16x16x32_bf16(A[1][ks], b0, acc2[nt], 0, 0, 0);
        acc2[nt] = __builtin_amdgcn_mfma_f32_16x16x32_bf16(A[0][ks], b1, acc2[nt], 0, 0, 0);
        acc2[nt] = __builtin_amdgcn_mfma_f32_16x16x32_bf16(A[2][ks], b0, acc2[nt], 0, 0, 0);
        acc2[nt] = __builtin_amdgcn_mfma_f32_16x16x32_bf16(A[0][ks], b2, acc2[nt], 0, 0, 0);
        acc2[nt] = __builtin_amdgcn_mfma_f32_16x16x32_bf16(A[1][ks], b1, acc2[nt], 0, 0, 0);
      }
      buf ^= 1;
    }
#pragma unroll
    for (int nt = 0; nt < 4; ++nt) {
      int code = n0 + nt * 16 + r;
      float cn = cbn[code];
#pragma unroll
      for (int j = 0; j < 4; ++j) {
        float d = cn - 2.f * (acc[nt][j] + acc2[nt][j]);
        if (d < bv[j]) { bv[j] = d; bi[j] = code; }
      }
    }
  }

#pragma unroll
  for (int m = 1; m < 16; m <<= 1) {
#pragma unroll
    for (int j = 0; j < 4; ++j) {
      float ov = __shfl_xor(bv[j], m, 64);
      int   oi = __shfl_xor(bi[j], m, 64);
      if (ov < bv[j] || (ov == bv[j] && oi < bi[j])) { bv[j] = ov; bi[j] = oi; }
    }
  }
  if (r == 0) {
#pragma unroll
    for (int j = 0; j < 4; ++j) s_idx[wv * 16 + kb * 4 + j] = bi[j];
  }
  __syncthreads();

  const int c = tid;
  float lsum = 0.f;
  for (int m2 = 0; m2 < 64; ++m2) {
    int w = s_idx[m2];
    long ro = (t0 + m2) * 256 + c;
    float nv = res[ro] - cb[(long)w * 256 + c];
    res[ro] = nv;
    lsum += nv * nv;
    if (WP) {
      u16 h = f2bf(nv);
      float r1 = nv - bf2f(h);
      u16 mm = f2bf(r1);
      resp[ro] = h;
      resp[16777216L + ro] = mm;
      resp[33554432L + ro] = f2bf(r1 - bf2f(mm));
    }
  }
  for (int off = 32; off; off >>= 1) lsum += __shfl_down(lsum, off, 64);
  if (ln == 0) s_ls[wv] = lsum;
  __syncthreads();
  if (tid == 0)
    atomicAdd(loss_out, (s_ls[0] + s_ls[1] + s_ls[2] + s_ls[3]) * (1.f/(65536.f*256.f)));
  if (tid < 64) {
    long tglob = t0 + tid;
    int b = (int)(tglob >> 12), hw = (int)(tglob & 4095);
    idx_out[(long)b * 16384 + hw] = (float)s_idx[tid];
  }
}

// ---------------------------------------------------------------------------
extern "C" void kernel_launch(void* const* d_in, const int* in_sizes, int n_in,
                              void* d_out, int out_size, void* d_ws, size_t ws_size,
                              hipStream_t stream) {
  const float* x      = (const float*)d_in[0];
  const float* ew1    = (const float*)d_in[1];
  const float* eb1    = (const float*)d_in[2];
  const float* ew2    = (const float*)d_in[3];
  const float* eb2    = (const float*)d_in[4];
  const float* ew3    = (const float*)d_in[5];
  const float* eb3    = (const float*)d_in[6];
  const float* ew4    = (const float*)d_in[7];
  const float* eb4    = (const float*)d_in[8];
  const float* cbooks = (const float*)d_in[9];
  const float* dw1    = (const float*)d_in[10];
  const float* db1    = (const float*)d_in[11];
  const float* dw2    = (const float*)d_in[12];
  const float* db2    = (const float*)d_in[13];
  const float* dw3    = (const float*)d_in[14];
  const float* db3    = (const float*)d_in[15];
  const float* dw4    = (const float*)d_in[16];
  const float* db4    = (const float*)d_in[17];

  float* out = (float*)d_out;
  float* o_recon = out;                  // (16,3,512,512)
  float* o_idx   = out + 12582912;       // (16,4,64,64)
  float* o_loss  = out + 12845056;       // (4,)
  float* o_q     = out + 12845060;       // (16,256,64,64)

  float* ws  = (float*)d_ws;
  // fp32 prep region
  float* wp2 = ws;                        // 131072
  float* wp3 = ws + 131072;               //  65536
  float* wp4 = ws + 196608;               //   3072
  float* cbn = ws + 199680;               //   4096
  // bf16 weight planes (u16), base at float offset 203776
  u16* wu   = (u16*)(ws + 203776);
  u16* e3w  = wu;                         // 3 x 294912
  u16* e4w  = wu + 884736;                // 3 x 589824
  u16* d1w  = wu + 2654208;               // 2 x 294912
  u16* t2w  = wu + 3244032;               // 4 x (2 x 32768)
  u16* t3w  = wu + 3506176;               // 4 x (2 x 16384)

  const long DA = 2097152;
  // encoder phase (parity planes + activations)
  u16*  P1  = (u16*)(ws + DA);            // 3 x 8,520,192 u16  (129*129*32*16)
  float* h1 = ws + DA + 12780288;         // 16,777,216
  u16*  P2  = (u16*)(ws + DA + 29557504); // 3 x 17,305,600 u16 (65*65*256*16)
  float* h2 = ws + DA + 55515904;         //  8,388,608
  u16* w1p  = (u16*)(ws + DA + 72000000); // 3 x 8192   (in z region, dead then)
  u16* w2p  = w1p + 24576;                // 3 x 131072
  float* h3  = ws + DA;                   // P1 dead
  float* z   = ws + DA + 58720256;        // 16,777,216
  float* zt  = ws + DA;                   // h3 dead
  float* res = ws + DA + 16777216;        // A4 dead
  u16* resp  = (u16*)(ws + DA + 33554432);// 3 x 16,777,216 u16
  u16* cbp   = (u16*)(ws + DA + 75497472);// 4 x 786,432 u16
  float* d1  = ws + DA;                   // zt dead
  float* d2  = ws + DA + 16777216;        // res dead
  float* d3  = ws + DA + 16777216;        // D3 consumed
  u16* A3 = (u16*)(ws + DA + 25165824);   // 3 x 8,388,608 u16 (h1/P2 dead)
  u16* A4 = (u16*)(ws + DA + 16777216);   // 3 x 16,777,216 u16
  u16* D1 = (u16*)(ws + DA + 33554432);   // 2 x 16,777,216 u16 (resp dead)
  u16* D2 = (u16*)(ws + DA + 8388608);    // 2 x 8,388,608 u16
  u16* D3 = (u16*)(ws + DA);              // 2 x 16,777,216 u16

  // ---------------- prep ----------------
  rearrange_convT<<<256, 256, 0, stream>>>(dw2, wp2, 128, 64);
  rearrange_convT<<<256, 256, 0, stream>>>(dw3, wp3, 64, 64);
  rearrange_convT<<<16, 256, 0, stream>>>(dw4, wp4, 64, 3);
  cb_norm<<<4096, 256, 0, stream>>>(cbooks, cbn);
  cbsplit<<<512, 256, 0, stream>>>(cbooks, cbp);
  zero4<<<1, 64, 0, stream>>>(o_loss);
  wsplit_s2<3,8><<<32, 256, 0, stream>>>(ew1, w1p, 8192L, 64);
  wsplit_s2<64,64><<<128, 256, 0, stream>>>(ew2, w2p, 131072L, 128);
  wsplit<3><<<256, 256, 0, stream>>>(ew3, e3w, 294912L, 256, 128, 9);
  wsplit<3><<<256, 256, 0, stream>>>(ew4, e4w, 589824L, 256, 256, 9);
  wsplit<2><<<256, 256, 0, stream>>>(dw1, d1w, 294912L, 128, 256, 9);
  for (int p = 0; p < 4; ++p) {
    wsplit<2><<<64, 256, 0, stream>>>(wp2 + p*32768, t2w + p*65536, 32768L, 64, 128, 4);
    wsplit<2><<<64, 256, 0, stream>>>(wp3 + p*16384, t3w + p*32768, 16384L, 64, 64, 4);
  }

  // ---------------- encoder (all MFMA now) ----------------
  par_nhwc<3,8><<<dim3(5,129,16), 256, 0, stream>>>(x, P1, 8520192L, 256, 256, 129);
  conv_mfma<2,2,1,3><<<dim3(256,1,16), 256, 0, stream>>>(
      P1, 8520192L, w1p, 8192L, eb1, h1,
      32, 129, 129, 64, 16, 0, 0, 0L, 1048576L, 16384L, 128L, 1L);

  par_nhwc<64,64><<<dim3(3,65,16), 256, 0, stream>>>(h1, P2, 17305600L, 128, 128, 65);
  conv_mfma<2,2,1,3><<<dim3(64,2,16), 256, 0, stream>>>(
      P2, 17305600L, w2p, 131072L, eb2, h2,
      256, 65, 65, 128, 8, 0, 0, 0L, 524288L, 4096L, 64L, 1L);

  to_nhwc_bf16<3><<<dim3(64,4,16), 256, 0, stream>>>(h2, A3, 8388608L, 128, 4096);
  conv_mfma<3,3,1,3><<<dim3(64,4,16), 256, 0, stream>>>(
      A3, 8388608L, e3w, 294912L, eb3, h3,
      128, 64, 64, 256, 8, 1, 1, 0L, 1048576L, 4096L, 64L, 1L);

  to_nhwc_bf16<3><<<dim3(64,8,16), 256, 0, stream>>>(h3, A4, 16777216L, 256, 4096);
  conv_mfma<3,3,0,3><<<dim3(64,4,16), 256, 0, stream>>>(
      A4, 16777216L, e4w, 589824L, eb4, z,
      256, 64, 64, 256, 8, 1, 1, 0L, 1048576L, 4096L, 64L, 1L);

  // ---------------- VQ ----------------
  transpose_zt<<<dim3(128,8,16), 256, 0, stream>>>(z, zt, res, resp);
  for (int l = 0; l < 3; ++l)
    vq_mfma<true><<<1024, 256, 0, stream>>>(cbp + (long)l*786432,
        cbooks + (long)l*262144, cbn + l*1024, res, resp,
        o_idx + l*4096, o_loss + l);
  vq_mfma<false><<<1024, 256, 0, stream>>>(cbp + 3L*786432,
      cbooks + 3L*262144, cbn + 3*1024, res, resp,
      o_idx + 3*4096, o_loss + 3);
  make_quantized<<<dim3(128,8,16), 256, 0, stream>>>(zt, res, o_q);

  // ---------------- decoder ----------------
  to_nhwc_bf16<2><<<dim3(64,8,16), 256, 0, stream>>>(o_q, D1, 16777216L, 256, 4096);
  conv_mfma<3,3,1,2><<<dim3(64,2,16), 256, 0, stream>>>(
      D1, 16777216L, d1w, 294912L, db1, d1,
      256, 64, 64, 128, 8, 1, 1, 0L, 524288L, 4096L, 64L, 1L);

  to_nhwc_bf16<2><<<dim3(64,4,16), 256, 0, stream>>>(d1, D2, 8388608L, 128, 4096);
  for (int p = 0; p < 4; ++p) {
    int py = p >> 1, px = p & 1;
    conv_mfma<2,2,1,2><<<dim3(64,1,16), 256, 0, stream>>>(
        D2, 8388608L, t2w + p*65536, 32768L, db2, d2,
        128, 64, 64, 64, 8, 1-py, 1-px,
        (long)(py*128 + px), 1048576L, 16384L, 256L, 2L);
  }

  to_nhwc_bf16<2><<<dim3(256,2,16), 256, 0, stream>>>(d2, D3, 16777216L, 64, 16384);
  for (int p = 0; p < 4; ++p) {
    int py = p >> 1, px = p & 1;
    conv_mfma<2,2,1,2><<<dim3(256,1,16), 256, 0, stream>>>(
        D3, 16777216L, t3w + p*32768, 16384L, db3, d3,
        64, 128, 128, 64, 16, 1-py, 1-px,
        (long)(py*256 + px), 4194304L, 65536L, 512L, 2L);
  }

  for (int p = 0; p < 4; ++p) {
    int py = p >> 1, px = p & 1;
    conv_tiled<4,16,16,2,2,1,2><<<dim3(256,1,16), 256, 0, stream>>>(
        d3, wp4 + p*768, db4, o_recon, 16, 64, 256, 256, 3, 16, 1-py, 1-px,
        (long)(py*512 + px), 786432L, 262144L, 1024L, 2L);
  }
  (void)in_sizes; (void)n_in; (void)out_size; (void)ws_size;
}